// Round 1
// baseline (769.197 us; speedup 1.0000x reference)
//
#include <hip/hip_runtime.h>
#include <math.h>

// ---------- problem constants ----------
constexpr int NN0 = 524288, NN1 = 65536, NN2 = 8192, NN3 = 1024;
constexpr int D0 = 100, D1 = 256, D2 = 256, D3 = 47;
constexpr int E0 = 655360, E1 = 81920, E2 = 10240;

static inline int cdiv(int a, int b) { return (a + b - 1) / b; }

// ---------- Pass A: per-dst degree count ----------
__global__ void count_kernel(const int* __restrict__ dst, int E, int* __restrict__ cnt) {
    int i = blockIdx.x * 256 + threadIdx.x;
    if (i < E) atomicAdd(&cnt[dst[i]], 1);
}

// ---------- Pass B: exclusive scan (single block, 1024 threads) ----------
__global__ __launch_bounds__(1024) void scan_kernel(const int* __restrict__ cnt, int n,
                                                    int* __restrict__ ofs, int* __restrict__ cursor) {
    __shared__ int s[1024];
    __shared__ int running;
    if (threadIdx.x == 0) running = 0;
    __syncthreads();
    for (int base = 0; base < n; base += 1024) {
        int i = base + threadIdx.x;
        int v = (i < n) ? cnt[i] : 0;
        s[threadIdx.x] = v;
        __syncthreads();
        // Hillis-Steele inclusive scan
        for (int off = 1; off < 1024; off <<= 1) {
            int t = (threadIdx.x >= off) ? s[threadIdx.x - off] : 0;
            __syncthreads();
            s[threadIdx.x] += t;
            __syncthreads();
        }
        int incl = s[threadIdx.x];
        int r = running;
        if (i < n) {
            int ex = r + incl - v;
            ofs[i] = ex;
            cursor[i] = ex;
        }
        __syncthreads();
        if (threadIdx.x == 1023) running = r + s[1023];
        __syncthreads();
    }
    if (threadIdx.x == 1023) ofs[n] = running;
}

// ---------- Pass C: scatter src ids into CSR slots ----------
__global__ void scatter_kernel(const int* __restrict__ src, const int* __restrict__ dst, int E,
                               int* __restrict__ cursor, int* __restrict__ perm) {
    int i = blockIdx.x * 256 + threadIdx.x;
    if (i < E) {
        int p = atomicAdd(&cursor[dst[i]], 1);
        perm[p] = src[i];
    }
}

// ---------- Pass D: mean-aggregate, one wave per dst row ----------
// generic-D scalar version (used for D=100)
__global__ void agg_scalar(const float* __restrict__ x, const int* __restrict__ perm,
                           const int* __restrict__ ofs, float* __restrict__ agg,
                           int nrows, int D) {
    int wave = (blockIdx.x * blockDim.x + threadIdx.x) >> 6;
    int lane = threadIdx.x & 63;
    if (wave >= nrows) return;
    int s0 = ofs[wave], s1 = ofs[wave + 1];
    float inv = 1.0f / fmaxf((float)(s1 - s0), 1.0f);
    for (int d = lane; d < D; d += 64) {
        float acc = 0.f;
        for (int e = s0; e < s1; e++) {
            acc += x[(size_t)perm[e] * D + d];
        }
        agg[(size_t)wave * D + d] = acc * inv;
    }
}

// D=256 float4 version: lane handles dims [4*lane, 4*lane+3]
__global__ void agg_vec4_256(const float* __restrict__ x, const int* __restrict__ perm,
                             const int* __restrict__ ofs, float* __restrict__ agg, int nrows) {
    int wave = (blockIdx.x * blockDim.x + threadIdx.x) >> 6;
    int lane = threadIdx.x & 63;
    if (wave >= nrows) return;
    int s0 = ofs[wave], s1 = ofs[wave + 1];
    float4 acc = make_float4(0.f, 0.f, 0.f, 0.f);
    for (int e = s0; e < s1; e++) {
        const float4* xr = (const float4*)(x + (size_t)perm[e] * 256);
        float4 v = xr[lane];
        acc.x += v.x; acc.y += v.y; acc.z += v.z; acc.w += v.w;
    }
    float inv = 1.0f / fmaxf((float)(s1 - s0), 1.0f);
    acc.x *= inv; acc.y *= inv; acc.z *= inv; acc.w *= inv;
    ((float4*)(agg + (size_t)wave * 256))[lane] = acc;
}

// ---------- fused dual GEMM: out = A1@W1 + A2@W2 + bias (+ReLU) ----------
// A1: M x K1, W1: K1 x N, A2: M x K2 (row stride K2), W2: K2 x N
template <int RELU>
__global__ __launch_bounds__(256) void gemm_dual(const float* __restrict__ A1, const float* __restrict__ W1, int K1,
                                                 const float* __restrict__ A2, const float* __restrict__ W2, int K2,
                                                 const float* __restrict__ bias, float* __restrict__ out,
                                                 int M, int N) {
    __shared__ float As[16][65];
    __shared__ float Bs[16][64];
    int tid = threadIdx.x;
    int tx = tid & 15, ty = tid >> 4;
    int bm = blockIdx.y * 64, bn = blockIdx.x * 64;
    float acc[4][4] = {};
    for (int pass = 0; pass < 2; ++pass) {
        const float* A = pass ? A2 : A1;
        const float* W = pass ? W2 : W1;
        int K = pass ? K2 : K1;
        for (int k0 = 0; k0 < K; k0 += 16) {
#pragma unroll
            for (int i = 0; i < 4; i++) {
                int L = i * 256 + tid;
                int m = L >> 4, k = L & 15;
                int gm = bm + m, gk = k0 + k;
                float v = 0.f;
                if (gm < M && gk < K) v = A[(size_t)gm * K + gk];
                As[k][m] = v;
            }
#pragma unroll
            for (int i = 0; i < 4; i++) {
                int L = i * 256 + tid;
                int n = L & 63, k = L >> 6;
                int gk = k0 + k, gn = bn + n;
                float v = 0.f;
                if (gk < K && gn < N) v = W[(size_t)gk * N + gn];
                Bs[k][n] = v;
            }
            __syncthreads();
#pragma unroll
            for (int k = 0; k < 16; k++) {
                float a[4], b[4];
#pragma unroll
                for (int i = 0; i < 4; i++) a[i] = As[k][ty * 4 + i];
#pragma unroll
                for (int j = 0; j < 4; j++) b[j] = Bs[k][tx * 4 + j];
#pragma unroll
                for (int i = 0; i < 4; i++)
#pragma unroll
                    for (int j = 0; j < 4; j++) acc[i][j] += a[i] * b[j];
            }
            __syncthreads();
        }
    }
#pragma unroll
    for (int i = 0; i < 4; i++) {
        int gm = bm + ty * 4 + i;
        if (gm >= M) continue;
#pragma unroll
        for (int j = 0; j < 4; j++) {
            int gn = bn + tx * 4 + j;
            if (gn >= N) continue;
            float v = acc[i][j] + bias[gn];
            if (RELU) v = fmaxf(v, 0.f);
            out[(size_t)gm * N + gn] = v;
        }
    }
}

// ---------- log_softmax, one wave per row (N <= 64) ----------
__global__ void logsoftmax_kernel(const float* __restrict__ logits, float* __restrict__ out, int M, int N) {
    int row = (blockIdx.x * blockDim.x + threadIdx.x) >> 6;
    int lane = threadIdx.x & 63;
    if (row >= M) return;
    float v = (lane < N) ? logits[(size_t)row * N + lane] : -1e30f;
    float m = v;
    for (int o = 32; o; o >>= 1) m = fmaxf(m, __shfl_xor(m, o));
    float e = (lane < N) ? expf(v - m) : 0.f;
    float s = e;
    for (int o = 32; o; o >>= 1) s += __shfl_xor(s, o);
    float ls = logf(s);
    if (lane < N) out[(size_t)row * N + lane] = v - m - ls;
}

extern "C" void kernel_launch(void* const* d_in, const int* in_sizes, int n_in,
                              void* d_out, int out_size, void* d_ws, size_t ws_size,
                              hipStream_t stream) {
    const float* x   = (const float*)d_in[0];
    const int* src0  = (const int*)d_in[1];
    const int* dst0  = (const int*)d_in[2];
    const int* src1  = (const int*)d_in[3];
    const int* dst1  = (const int*)d_in[4];
    const int* src2  = (const int*)d_in[5];
    const int* dst2  = (const int*)d_in[6];
    const float* Wl0 = (const float*)d_in[7];
    const float* bl0 = (const float*)d_in[8];
    const float* Wr0 = (const float*)d_in[9];
    const float* Wl1 = (const float*)d_in[10];
    const float* bl1 = (const float*)d_in[11];
    const float* Wr1 = (const float*)d_in[12];
    const float* Wl2 = (const float*)d_in[13];
    const float* bl2 = (const float*)d_in[14];
    const float* Wr2 = (const float*)d_in[15];
    float* out = (float*)d_out;

    // ---- workspace layout (floats/ints) ----
    float* h1     = (float*)d_ws;                 // 65536*256
    float* h2     = h1 + (size_t)NN1 * D1;        // 8192*256
    float* agg    = h2 + (size_t)NN2 * D2;        // max 65536*100
    float* logits = agg + (size_t)NN1 * D0;       // 1024*47
    int* cnt      = (int*)(logits + (size_t)NN3 * D3);  // 65536
    int* ofs      = cnt + NN1;                    // 65537
    int* cursor   = ofs + NN1 + 1;                // 65537
    int* perm     = cursor + NN1 + 1;             // 655360

    const int* srcs[3] = {src0, src1, src2};
    const int* dsts[3] = {dst0, dst1, dst2};
    const int Es[3]    = {E0, E1, E2};
    const int ndst[3]  = {NN1, NN2, NN3};
    const int din[3]   = {D0, D1, D2};

    const float* h_prev = x;

    for (int l = 0; l < 3; ++l) {
        int E = Es[l], nd = ndst[l], D = din[l];
        // zero counts
        hipMemsetAsync(cnt, 0, (size_t)nd * sizeof(int), stream);
        // CSR build
        count_kernel<<<cdiv(E, 256), 256, 0, stream>>>(dsts[l], E, cnt);
        scan_kernel<<<1, 1024, 0, stream>>>(cnt, nd, ofs, cursor);
        scatter_kernel<<<cdiv(E, 256), 256, 0, stream>>>(srcs[l], dsts[l], E, cursor, perm);
        // aggregate (mean)
        int waves_blocks = cdiv(nd * 64, 256);
        if (D == 256) {
            agg_vec4_256<<<waves_blocks, 256, 0, stream>>>(h_prev, perm, ofs, agg, nd);
        } else {
            agg_scalar<<<waves_blocks, 256, 0, stream>>>(h_prev, perm, ofs, agg, nd, D);
        }
        // fused dual GEMM
        if (l == 0) {
            dim3 grid(cdiv(D1, 64), cdiv(NN1, 64));
            gemm_dual<1><<<grid, 256, 0, stream>>>(agg, Wl0, D0, x, Wr0, D0, bl0, h1, NN1, D1);
            h_prev = h1;
        } else if (l == 1) {
            dim3 grid(cdiv(D2, 64), cdiv(NN2, 64));
            gemm_dual<1><<<grid, 256, 0, stream>>>(agg, Wl1, D1, h1, Wr1, D1, bl1, h2, NN2, D2);
            h_prev = h2;
        } else {
            dim3 grid(cdiv(D3, 64), cdiv(NN3, 64));
            gemm_dual<0><<<grid, 256, 0, stream>>>(agg, Wl2, D2, h2, Wr2, D2, bl2, logits, NN3, D3);
        }
    }
    // log_softmax over the last layer
    logsoftmax_kernel<<<cdiv(NN3 * 64, 256), 256, 0, stream>>>(logits, out, NN3, D3);
}

// Round 2
// 365.172 us; speedup vs baseline: 2.1064x; 2.1064x over previous
//
#include <hip/hip_runtime.h>
#include <math.h>

// ---------- problem constants ----------
constexpr int NN1 = 65536, NN2 = 8192, NN3 = 1024;
constexpr int E0 = 655360;

static inline int cdiv(int a, int b) { return (a + b - 1) / b; }

typedef __bf16 bf16x8_t __attribute__((ext_vector_type(8)));
typedef float f32x4_t __attribute__((ext_vector_type(4)));

// float -> bf16 (RNE) as raw ushort
__device__ __forceinline__ unsigned short f2bf(float f) {
    union { float f; unsigned int u; } v; v.f = f;
    unsigned int r = v.u + 0x7fffu + ((v.u >> 16) & 1u);
    return (unsigned short)(r >> 16);
}
__device__ __forceinline__ float bf2f(unsigned short h) {
    union { unsigned int u; float f; } v; v.u = ((unsigned int)h) << 16;
    return v.f;
}

// ---------- CSR build ----------
__global__ void count_kernel(const int* __restrict__ dst, int E, int* __restrict__ cnt) {
    int i = blockIdx.x * 256 + threadIdx.x;
    if (i < E) atomicAdd(&cnt[dst[i]], 1);
}

// phase 1: per-1024-chunk exclusive scan (into ofs), chunk sums out
__global__ __launch_bounds__(1024) void scan1(const int* __restrict__ cnt, int n,
                                              int* __restrict__ ofs, int* __restrict__ sums) {
    __shared__ int s[1024];
    int i = blockIdx.x * 1024 + threadIdx.x;
    int v = (i < n) ? cnt[i] : 0;
    s[threadIdx.x] = v;
    __syncthreads();
    for (int off = 1; off < 1024; off <<= 1) {
        int t = (threadIdx.x >= off) ? s[threadIdx.x - off] : 0;
        __syncthreads();
        s[threadIdx.x] += t;
        __syncthreads();
    }
    if (i < n) ofs[i] = s[threadIdx.x] - v;     // exclusive within chunk
    if (threadIdx.x == 1023) sums[blockIdx.x] = s[1023];
}

// phase 2: single-wave exclusive scan of chunk sums (nb <= 64); total -> ofs[n]
__global__ void scan2(int* __restrict__ sums, int nb, int* __restrict__ ofs, int n) {
    int lane = threadIdx.x;   // 64 threads
    int v = (lane < nb) ? sums[lane] : 0;
    int incl = v;
    for (int off = 1; off < 64; off <<= 1) {
        int t = __shfl_up(incl, off);
        if (lane >= off) incl += t;
    }
    if (lane < nb) sums[lane] = incl - v;       // exclusive chunk offset
    if (lane == 63) ofs[n] = incl;              // grand total
}

// phase 3: add chunk offsets, fill cursor
__global__ void scan3(const int* __restrict__ sums, int n,
                      int* __restrict__ ofs, int* __restrict__ cursor) {
    int i = blockIdx.x * 256 + threadIdx.x;
    if (i < n) {
        int v = ofs[i] + sums[i >> 10];
        ofs[i] = v;
        cursor[i] = v;
    }
}

__global__ void scatter_kernel(const int* __restrict__ src, const int* __restrict__ dst, int E,
                               int* __restrict__ cursor, int* __restrict__ perm) {
    int i = blockIdx.x * 256 + threadIdx.x;
    if (i < E) {
        int p = atomicAdd(&cursor[dst[i]], 1);
        perm[p] = src[i];
    }
}

// ---------- layer-0 aggregate: x fp32 (D=100) -> Abig0 row [agg(128) | x_dst(128)] bf16 ----------
__global__ void agg0_kernel(const float* __restrict__ x, const int* __restrict__ perm,
                            const int* __restrict__ ofs, unsigned short* __restrict__ Ab, int nrows) {
    int wave = (blockIdx.x * blockDim.x + threadIdx.x) >> 6;
    int lane = threadIdx.x & 63;
    if (wave >= nrows) return;
    int s0 = ofs[wave], s1 = ofs[wave + 1];
    float inv = 1.0f / fmaxf((float)(s1 - s0), 1.0f);
    float a0 = 0.f, a1 = 0.f;
    for (int e = s0; e < s1; e++) {
        const float* xr = x + (size_t)perm[e] * 100;
        a0 += xr[lane];
        if (lane < 36) a1 += xr[64 + lane];
    }
    unsigned short* row = Ab + (size_t)wave * 256;
    row[lane] = f2bf(a0 * inv);
    row[64 + lane] = (lane < 36) ? f2bf(a1 * inv) : (unsigned short)0;   // zero-pads 100..127
    const float* xd = x + (size_t)wave * 100;
    row[128 + lane] = f2bf(xd[lane]);
    row[192 + lane] = (lane < 36) ? f2bf(xd[64 + lane]) : (unsigned short)0;  // zero-pads 228..255
}

// ---------- layer-1 aggregate: h1 bf16 (D=256) -> Abig1 row [agg(256) | h_dst(256)] bf16 ----------
__global__ void agg1_kernel(const unsigned short* __restrict__ h, const int* __restrict__ perm,
                            const int* __restrict__ ofs, unsigned short* __restrict__ Ab, int nrows) {
    int wave = (blockIdx.x * blockDim.x + threadIdx.x) >> 6;
    int lane = threadIdx.x & 63;
    if (wave >= nrows) return;
    int s0 = ofs[wave], s1 = ofs[wave + 1];
    float inv = 1.0f / fmaxf((float)(s1 - s0), 1.0f);
    float a0 = 0.f, a1 = 0.f, a2 = 0.f, a3 = 0.f;
    for (int e = s0; e < s1; e++) {
        const ushort4 v = *reinterpret_cast<const ushort4*>(h + (size_t)perm[e] * 256 + lane * 4);
        a0 += bf2f(v.x); a1 += bf2f(v.y); a2 += bf2f(v.z); a3 += bf2f(v.w);
    }
    ushort4 o;
    o.x = f2bf(a0 * inv); o.y = f2bf(a1 * inv); o.z = f2bf(a2 * inv); o.w = f2bf(a3 * inv);
    *reinterpret_cast<ushort4*>(Ab + (size_t)wave * 512 + lane * 4) = o;
    *reinterpret_cast<ushort4*>(Ab + (size_t)wave * 512 + 256 + lane * 4) =
        *reinterpret_cast<const ushort4*>(h + (size_t)wave * 256 + lane * 4);
}

// ---------- layer-2 aggregate: h2 fp32 (D=256), float4 per lane ----------
__global__ void agg_vec4_256(const float* __restrict__ x, const int* __restrict__ perm,
                             const int* __restrict__ ofs, float* __restrict__ agg, int nrows) {
    int wave = (blockIdx.x * blockDim.x + threadIdx.x) >> 6;
    int lane = threadIdx.x & 63;
    if (wave >= nrows) return;
    int s0 = ofs[wave], s1 = ofs[wave + 1];
    float4 acc = make_float4(0.f, 0.f, 0.f, 0.f);
    for (int e = s0; e < s1; e++) {
        const float4* xr = (const float4*)(x + (size_t)perm[e] * 256);
        float4 v = xr[lane];
        acc.x += v.x; acc.y += v.y; acc.z += v.z; acc.w += v.w;
    }
    float inv = 1.0f / fmaxf((float)(s1 - s0), 1.0f);
    acc.x *= inv; acc.y *= inv; acc.z *= inv; acc.w *= inv;
    ((float4*)(agg + (size_t)wave * 256))[lane] = acc;
}

// ---------- weight prep: Wt[n][k] bf16, zero-padded, dual-K concat ----------
__global__ void prep_w0(const float* __restrict__ Wl, const float* __restrict__ Wr,
                        unsigned short* __restrict__ Wt) {
    int idx = blockIdx.x * 256 + threadIdx.x;     // 256 n x 256 k
    int n = idx >> 8, k = idx & 255;
    float v = 0.f;
    if (k < 100) v = Wl[k * 256 + n];
    else if (k >= 128 && k < 228) v = Wr[(k - 128) * 256 + n];
    Wt[idx] = f2bf(v);
}
__global__ void prep_w1(const float* __restrict__ Wl, const float* __restrict__ Wr,
                        unsigned short* __restrict__ Wt) {
    int idx = blockIdx.x * 256 + threadIdx.x;     // 256 n x 512 k
    int n = idx >> 9, k = idx & 511;
    float v = (k < 256) ? Wl[k * 256 + n] : Wr[(k - 256) * 256 + n];
    Wt[idx] = f2bf(v);
}

// ---------- bf16 MFMA GEMM: out = A @ Wt^T + bias (+ReLU) ----------
// A: M x K bf16 row-major; Wt: N x K bf16 (pre-transposed weights)
// BM=128 BN=128 BK=32, 4 waves, each wave 64x64 (4x4 fragments of 16x16x32)
template <int OUT_BF16, int RELU>
__global__ __launch_bounds__(256) void mfma_gemm(const unsigned short* __restrict__ A,
                                                 const unsigned short* __restrict__ Wt,
                                                 const float* __restrict__ bias,
                                                 void* __restrict__ outp,
                                                 int M, int N, int K) {
    __shared__ unsigned short As[128][40];   // +8 pad: 80B row stride, 16B-aligned, 2-way banks
    __shared__ unsigned short Bs[128][40];
    int tid = threadIdx.x;
    int lane = tid & 63, wid = tid >> 6;
    int wm = (wid & 1) * 64, wn = (wid >> 1) * 64;
    int bm = blockIdx.y * 128, bn = blockIdx.x * 128;

    f32x4_t acc[4][4];
#pragma unroll
    for (int i = 0; i < 4; i++)
#pragma unroll
        for (int j = 0; j < 4; j++)
#pragma unroll
            for (int r = 0; r < 4; r++) acc[i][j][r] = 0.f;

    int r0 = lane & 15, kg = lane >> 4;     // fragment row/col-within-16, k-group

    for (int k0 = 0; k0 < K; k0 += 32) {
        // stage A tile (128 x 32 bf16 = 8 KB): 512 x 16B chunks, 2 per thread
        {
            int c = tid;
            int row = c >> 2, k8 = (c & 3) << 3;
            *reinterpret_cast<int4*>(&As[row][k8]) =
                *reinterpret_cast<const int4*>(&A[(size_t)(bm + row) * K + k0 + k8]);
            c = tid + 256;
            row = c >> 2; k8 = (c & 3) << 3;
            *reinterpret_cast<int4*>(&As[row][k8]) =
                *reinterpret_cast<const int4*>(&A[(size_t)(bm + row) * K + k0 + k8]);
        }
        {
            int c = tid;
            int row = c >> 2, k8 = (c & 3) << 3;
            *reinterpret_cast<int4*>(&Bs[row][k8]) =
                *reinterpret_cast<const int4*>(&Wt[(size_t)(bn + row) * K + k0 + k8]);
            c = tid + 256;
            row = c >> 2; k8 = (c & 3) << 3;
            *reinterpret_cast<int4*>(&Bs[row][k8]) =
                *reinterpret_cast<const int4*>(&Wt[(size_t)(bn + row) * K + k0 + k8]);
        }
        __syncthreads();

        bf16x8_t af[4], bfv[4];
#pragma unroll
        for (int mi = 0; mi < 4; mi++)
            af[mi] = *reinterpret_cast<const bf16x8_t*>(&As[wm + mi * 16 + r0][kg * 8]);
#pragma unroll
        for (int ni = 0; ni < 4; ni++)
            bfv[ni] = *reinterpret_cast<const bf16x8_t*>(&Bs[wn + ni * 16 + r0][kg * 8]);
#pragma unroll
        for (int mi = 0; mi < 4; mi++)
#pragma unroll
            for (int ni = 0; ni < 4; ni++)
                acc[mi][ni] = __builtin_amdgcn_mfma_f32_16x16x32_bf16(af[mi], bfv[ni], acc[mi][ni], 0, 0, 0);
        __syncthreads();
    }

    // epilogue: C/D layout col=lane&15, row=(lane>>4)*4+j  [m89-verified]
    int cc = lane & 15, rr = (lane >> 4) * 4;
#pragma unroll
    for (int mi = 0; mi < 4; mi++) {
#pragma unroll
        for (int ni = 0; ni < 4; ni++) {
            int col = bn + wn + ni * 16 + cc;
            float b = bias[col];
#pragma unroll
            for (int j = 0; j < 4; j++) {
                int row = bm + wm + mi * 16 + rr + j;
                float v = acc[mi][ni][j] + b;
                if (RELU) v = fmaxf(v, 0.f);
                if (OUT_BF16)
                    ((unsigned short*)outp)[(size_t)row * N + col] = f2bf(v);
                else
                    ((float*)outp)[(size_t)row * N + col] = v;
            }
        }
    }
}

// ---------- fp32 dual GEMM (layer 2 only: M=1024, N=47, K=256+256) ----------
template <int RELU>
__global__ __launch_bounds__(256) void gemm_dual(const float* __restrict__ A1, const float* __restrict__ W1, int K1,
                                                 const float* __restrict__ A2, const float* __restrict__ W2, int K2,
                                                 const float* __restrict__ bias, float* __restrict__ out,
                                                 int M, int N) {
    __shared__ float As[16][65];
    __shared__ float Bs[16][64];
    int tid = threadIdx.x;
    int tx = tid & 15, ty = tid >> 4;
    int bm = blockIdx.y * 64, bn = blockIdx.x * 64;
    float acc[4][4] = {};
    for (int pass = 0; pass < 2; ++pass) {
        const float* A = pass ? A2 : A1;
        const float* W = pass ? W2 : W1;
        int K = pass ? K2 : K1;
        for (int k0 = 0; k0 < K; k0 += 16) {
#pragma unroll
            for (int i = 0; i < 4; i++) {
                int L = i * 256 + tid;
                int m = L >> 4, k = L & 15;
                int gm = bm + m, gk = k0 + k;
                float v = 0.f;
                if (gm < M && gk < K) v = A[(size_t)gm * K + gk];
                As[k][m] = v;
            }
#pragma unroll
            for (int i = 0; i < 4; i++) {
                int L = i * 256 + tid;
                int n = L & 63, k = L >> 6;
                int gk = k0 + k, gn = bn + n;
                float v = 0.f;
                if (gk < K && gn < N) v = W[(size_t)gk * N + gn];
                Bs[k][n] = v;
            }
            __syncthreads();
#pragma unroll
            for (int k = 0; k < 16; k++) {
                float a[4], b[4];
#pragma unroll
                for (int i = 0; i < 4; i++) a[i] = As[k][ty * 4 + i];
#pragma unroll
                for (int j = 0; j < 4; j++) b[j] = Bs[k][tx * 4 + j];
#pragma unroll
                for (int i = 0; i < 4; i++)
#pragma unroll
                    for (int j = 0; j < 4; j++) acc[i][j] += a[i] * b[j];
            }
            __syncthreads();
        }
    }
#pragma unroll
    for (int i = 0; i < 4; i++) {
        int gm = bm + ty * 4 + i;
        if (gm >= M) continue;
#pragma unroll
        for (int j = 0; j < 4; j++) {
            int gn = bn + tx * 4 + j;
            if (gn >= N) continue;
            float v = acc[i][j] + bias[gn];
            if (RELU) v = fmaxf(v, 0.f);
            out[(size_t)gm * N + gn] = v;
        }
    }
}

// ---------- log_softmax, one wave per row (N <= 64) ----------
__global__ void logsoftmax_kernel(const float* __restrict__ logits, float* __restrict__ out, int M, int N) {
    int row = (blockIdx.x * blockDim.x + threadIdx.x) >> 6;
    int lane = threadIdx.x & 63;
    if (row >= M) return;
    float v = (lane < N) ? logits[(size_t)row * N + lane] : -1e30f;
    float m = v;
    for (int o = 32; o; o >>= 1) m = fmaxf(m, __shfl_xor(m, o));
    float e = (lane < N) ? expf(v - m) : 0.f;
    float s = e;
    for (int o = 32; o; o >>= 1) s += __shfl_xor(s, o);
    float ls = logf(s);
    if (lane < N) out[(size_t)row * N + lane] = v - m - ls;
}

extern "C" void kernel_launch(void* const* d_in, const int* in_sizes, int n_in,
                              void* d_out, int out_size, void* d_ws, size_t ws_size,
                              hipStream_t stream) {
    const float* x   = (const float*)d_in[0];
    const int* src0  = (const int*)d_in[1];
    const int* dst0  = (const int*)d_in[2];
    const int* src1  = (const int*)d_in[3];
    const int* dst1  = (const int*)d_in[4];
    const int* src2  = (const int*)d_in[5];
    const int* dst2  = (const int*)d_in[6];
    const float* Wl0 = (const float*)d_in[7];
    const float* bl0 = (const float*)d_in[8];
    const float* Wr0 = (const float*)d_in[9];
    const float* Wl1 = (const float*)d_in[10];
    const float* bl1 = (const float*)d_in[11];
    const float* Wr1 = (const float*)d_in[12];
    const float* Wl2 = (const float*)d_in[13];
    const float* bl2 = (const float*)d_in[14];
    const float* Wr2 = (const float*)d_in[15];
    float* out = (float*)d_out;

    // ---- workspace layout ----
    char* p = (char*)d_ws;
    auto alloc = [&](size_t bytes) { char* r = p; p += (bytes + 255) & ~(size_t)255; return r; };
    unsigned short* Ab0 = (unsigned short*)alloc((size_t)NN1 * 256 * 2);  // [agg|x_dst] bf16
    unsigned short* h1  = (unsigned short*)alloc((size_t)NN1 * 256 * 2);  // layer-0 out bf16
    unsigned short* Ab1 = (unsigned short*)alloc((size_t)NN2 * 512 * 2);  // [agg1|h1_dst] bf16
    float* h2    = (float*)alloc((size_t)NN2 * 256 * 4);                  // layer-1 out fp32
    float* agg2  = (float*)alloc((size_t)NN3 * 256 * 4);
    float* logits= (float*)alloc((size_t)NN3 * 47 * 4);
    unsigned short* Wt0 = (unsigned short*)alloc(256 * 256 * 2);
    unsigned short* Wt1 = (unsigned short*)alloc(256 * 512 * 2);
    int* cnt    = (int*)alloc((size_t)NN1 * 4);
    int* ofs    = (int*)alloc((size_t)(NN1 + 1) * 4);
    int* cursor = (int*)alloc((size_t)(NN1 + 1) * 4);
    int* sums   = (int*)alloc(64 * 4);
    int* perm   = (int*)alloc((size_t)E0 * 4);

    auto build_csr = [&](const int* src, const int* dst, int E, int nd) {
        hipMemsetAsync(cnt, 0, (size_t)nd * 4, stream);
        count_kernel<<<cdiv(E, 256), 256, 0, stream>>>(dst, E, cnt);
        int nb = cdiv(nd, 1024);
        scan1<<<nb, 1024, 0, stream>>>(cnt, nd, ofs, sums);
        scan2<<<1, 64, 0, stream>>>(sums, nb, ofs, nd);
        scan3<<<cdiv(nd, 256), 256, 0, stream>>>(sums, nd, ofs, cursor);
        scatter_kernel<<<cdiv(E, 256), 256, 0, stream>>>(src, dst, E, cursor, perm);
    };

    // weight prep
    prep_w0<<<256, 256, 0, stream>>>(Wl0, Wr0, Wt0);
    prep_w1<<<512, 256, 0, stream>>>(Wl1, Wr1, Wt1);

    // ---- layer 0 ----
    build_csr(src0, dst0, 655360, NN1);
    agg0_kernel<<<cdiv(NN1 * 64, 256), 256, 0, stream>>>(x, perm, ofs, Ab0, NN1);
    {
        dim3 grid(256 / 128, NN1 / 128);
        mfma_gemm<1, 1><<<grid, 256, 0, stream>>>(Ab0, Wt0, bl0, h1, NN1, 256, 256);
    }

    // ---- layer 1 ----
    build_csr(src1, dst1, 81920, NN2);
    agg1_kernel<<<cdiv(NN2 * 64, 256), 256, 0, stream>>>(h1, perm, ofs, Ab1, NN2);
    {
        dim3 grid(256 / 128, NN2 / 128);
        mfma_gemm<0, 1><<<grid, 256, 0, stream>>>(Ab1, Wt1, bl1, h2, NN2, 256, 512);
    }

    // ---- layer 2 (fp32 for final precision) ----
    build_csr(src2, dst2, 10240, NN3);
    agg_vec4_256<<<cdiv(NN3 * 64, 256), 256, 0, stream>>>(h2, perm, ofs, agg2, NN3);
    {
        dim3 grid(cdiv(47, 64), cdiv(NN3, 64));
        gemm_dual<0><<<grid, 256, 0, stream>>>(agg2, Wl2, 256, h2, Wr2, 256, bl2, logits, NN3, 47);
    }

    logsoftmax_kernel<<<cdiv(NN3 * 64, 256), 256, 0, stream>>>(logits, out, NN3, 47);
}

// Round 3
// 309.025 us; speedup vs baseline: 2.4891x; 1.1817x over previous
//
#include <hip/hip_runtime.h>
#include <math.h>

// ---------- problem constants ----------
constexpr int NN1 = 65536, NN2 = 8192, NN3 = 1024;
constexpr int E0 = 655360, E1 = 81920, E2 = 10240;
constexpr int ETOT = E0 + E1 + E2;           // 747520
constexpr int NTOT = NN1 + NN2 + NN3;        // 74752

static inline int cdiv(int a, int b) { return (a + b - 1) / b; }

typedef __bf16 bf16x8_t __attribute__((ext_vector_type(8)));
typedef float f32x4_t __attribute__((ext_vector_type(4)));

__device__ __forceinline__ unsigned short f2bf(float f) {
    union { float f; unsigned int u; } v; v.f = f;
    unsigned int r = v.u + 0x7fffu + ((v.u >> 16) & 1u);
    return (unsigned short)(r >> 16);
}
__device__ __forceinline__ float bf2f(unsigned short h) {
    union { unsigned int u; float f; } v; v.u = ((unsigned int)h) << 16;
    return v.f;
}

// ---------- fused CSR build (all 3 layers share one count/scan/scatter) ----------
__global__ void count_all(const int* __restrict__ dst0, const int* __restrict__ dst1,
                          const int* __restrict__ dst2, int* __restrict__ cnt) {
    int i = blockIdx.x * 256 + threadIdx.x;
    if (i < E0) atomicAdd(&cnt[dst0[i]], 1);
    else if (i < E0 + E1) atomicAdd(&cnt[NN1 + dst1[i - E0]], 1);
    else if (i < ETOT) atomicAdd(&cnt[NN1 + NN2 + dst2[i - E0 - E1]], 1);
}

// phase 1: per-1024-chunk exclusive scan, chunk sums out
__global__ __launch_bounds__(1024) void scan1(const int* __restrict__ cnt, int n,
                                              int* __restrict__ ofs, int* __restrict__ sums) {
    __shared__ int s[1024];
    int i = blockIdx.x * 1024 + threadIdx.x;
    int v = (i < n) ? cnt[i] : 0;
    s[threadIdx.x] = v;
    __syncthreads();
    for (int off = 1; off < 1024; off <<= 1) {
        int t = (threadIdx.x >= off) ? s[threadIdx.x - off] : 0;
        __syncthreads();
        s[threadIdx.x] += t;
        __syncthreads();
    }
    if (i < n) ofs[i] = s[threadIdx.x] - v;
    if (threadIdx.x == 1023) sums[blockIdx.x] = s[1023];
}

// phase 2: 128-thread block scan of chunk sums (nb <= 128)
__global__ void scan2(int* __restrict__ sums, int nb, int* __restrict__ ofs, int n) {
    __shared__ int s[128];
    int t = threadIdx.x;
    int v = (t < nb) ? sums[t] : 0;
    s[t] = v;
    __syncthreads();
    for (int off = 1; off < 128; off <<= 1) {
        int tv = (t >= off) ? s[t - off] : 0;
        __syncthreads();
        s[t] += tv;
        __syncthreads();
    }
    if (t < nb) sums[t] = s[t] - v;
    if (t == 127) ofs[n] = s[127];
}

// phase 3: add chunk offsets, fill cursor
__global__ void scan3(const int* __restrict__ sums, int n,
                      int* __restrict__ ofs, int* __restrict__ cursor) {
    int i = blockIdx.x * 256 + threadIdx.x;
    if (i < n) {
        int v = ofs[i] + sums[i >> 10];
        ofs[i] = v;
        cursor[i] = v;
    }
}

__global__ void scatter_all(const int* __restrict__ src0, const int* __restrict__ dst0,
                            const int* __restrict__ src1, const int* __restrict__ dst1,
                            const int* __restrict__ src2, const int* __restrict__ dst2,
                            int* __restrict__ cursor, int* __restrict__ perm) {
    int i = blockIdx.x * 256 + threadIdx.x;
    if (i < E0) {
        int p = atomicAdd(&cursor[dst0[i]], 1);
        perm[p] = src0[i];
    } else if (i < E0 + E1) {
        int j = i - E0;
        int p = atomicAdd(&cursor[NN1 + dst1[j]], 1);
        perm[p] = src1[j];
    } else if (i < ETOT) {
        int j = i - E0 - E1;
        int p = atomicAdd(&cursor[NN1 + NN2 + dst2[j]], 1);
        perm[p] = src2[j];
    }
}

// ---------- layer-0 aggregate: float4 gather, unroll x4 for MLP ----------
// x rows are 400 B, 16B-aligned (400 = 25*16). Lanes 0..24 each load one float4.
// Output row: [agg bf16 0..127 | x_dst bf16 128..255], dims 100..127 / 228..255 zero.
__global__ void agg0_kernel(const float* __restrict__ x, const int* __restrict__ perm,
                            const int* __restrict__ ofs, unsigned short* __restrict__ Ab, int nrows) {
    int wave = (blockIdx.x * blockDim.x + threadIdx.x) >> 6;
    int lane = threadIdx.x & 63;
    if (wave >= nrows) return;
    int s0 = ofs[wave], s1 = ofs[wave + 1];
    float inv = 1.0f / fmaxf((float)(s1 - s0), 1.0f);
    bool act = lane < 25;
    f32x4_t A0 = {0.f, 0.f, 0.f, 0.f}, A1 = A0, A2 = A0, A3 = A0;
    int e = s0;
    for (; e + 4 <= s1; e += 4) {
        int p0 = perm[e], p1 = perm[e + 1], p2 = perm[e + 2], p3 = perm[e + 3];
        if (act) {
            f32x4_t v0 = *reinterpret_cast<const f32x4_t*>(x + (size_t)p0 * 100 + lane * 4);
            f32x4_t v1 = *reinterpret_cast<const f32x4_t*>(x + (size_t)p1 * 100 + lane * 4);
            f32x4_t v2 = *reinterpret_cast<const f32x4_t*>(x + (size_t)p2 * 100 + lane * 4);
            f32x4_t v3 = *reinterpret_cast<const f32x4_t*>(x + (size_t)p3 * 100 + lane * 4);
            A0 += v0; A1 += v1; A2 += v2; A3 += v3;
        }
    }
    for (; e < s1; ++e) {
        int p = perm[e];
        if (act) A0 += *reinterpret_cast<const f32x4_t*>(x + (size_t)p * 100 + lane * 4);
    }
    f32x4_t a = (A0 + A1) + (A2 + A3);
    unsigned short* row = Ab + (size_t)wave * 256;
    ushort4 z = make_ushort4(0, 0, 0, 0);
    if (act) {
        ushort4 o;
        o.x = f2bf(a[0] * inv); o.y = f2bf(a[1] * inv);
        o.z = f2bf(a[2] * inv); o.w = f2bf(a[3] * inv);
        *reinterpret_cast<ushort4*>(row + lane * 4) = o;
        f32x4_t d = *reinterpret_cast<const f32x4_t*>(x + (size_t)wave * 100 + lane * 4);
        ushort4 od;
        od.x = f2bf(d[0]); od.y = f2bf(d[1]); od.z = f2bf(d[2]); od.w = f2bf(d[3]);
        *reinterpret_cast<ushort4*>(row + 128 + lane * 4) = od;
    } else if (lane < 32) {
        *reinterpret_cast<ushort4*>(row + lane * 4) = z;        // zero 100..127
        *reinterpret_cast<ushort4*>(row + 128 + lane * 4) = z;  // zero 228..255
    }
}

// ---------- layer-1 aggregate: h1 bf16 (D=256), unroll x2 ----------
__global__ void agg1_kernel(const unsigned short* __restrict__ h, const int* __restrict__ perm,
                            const int* __restrict__ ofs, unsigned short* __restrict__ Ab, int nrows) {
    int wave = (blockIdx.x * blockDim.x + threadIdx.x) >> 6;
    int lane = threadIdx.x & 63;
    if (wave >= nrows) return;
    int s0 = ofs[wave], s1 = ofs[wave + 1];
    float inv = 1.0f / fmaxf((float)(s1 - s0), 1.0f);
    float a0 = 0.f, a1 = 0.f, a2 = 0.f, a3 = 0.f;
    float b0 = 0.f, b1 = 0.f, b2 = 0.f, b3 = 0.f;
    int e = s0;
    for (; e + 2 <= s1; e += 2) {
        int p0 = perm[e], p1 = perm[e + 1];
        ushort4 v0 = *reinterpret_cast<const ushort4*>(h + (size_t)p0 * 256 + lane * 4);
        ushort4 v1 = *reinterpret_cast<const ushort4*>(h + (size_t)p1 * 256 + lane * 4);
        a0 += bf2f(v0.x); a1 += bf2f(v0.y); a2 += bf2f(v0.z); a3 += bf2f(v0.w);
        b0 += bf2f(v1.x); b1 += bf2f(v1.y); b2 += bf2f(v1.z); b3 += bf2f(v1.w);
    }
    if (e < s1) {
        ushort4 v = *reinterpret_cast<const ushort4*>(h + (size_t)perm[e] * 256 + lane * 4);
        a0 += bf2f(v.x); a1 += bf2f(v.y); a2 += bf2f(v.z); a3 += bf2f(v.w);
    }
    ushort4 o;
    o.x = f2bf((a0 + b0) * inv); o.y = f2bf((a1 + b1) * inv);
    o.z = f2bf((a2 + b2) * inv); o.w = f2bf((a3 + b3) * inv);
    *reinterpret_cast<ushort4*>(Ab + (size_t)wave * 512 + lane * 4) = o;
    *reinterpret_cast<ushort4*>(Ab + (size_t)wave * 512 + 256 + lane * 4) =
        *reinterpret_cast<const ushort4*>(h + (size_t)wave * 256 + lane * 4);
}

// ---------- layer-2 aggregate: h2 fp32 (D=256), float4 per lane ----------
__global__ void agg_vec4_256(const float* __restrict__ x, const int* __restrict__ perm,
                             const int* __restrict__ ofs, float* __restrict__ agg, int nrows) {
    int wave = (blockIdx.x * blockDim.x + threadIdx.x) >> 6;
    int lane = threadIdx.x & 63;
    if (wave >= nrows) return;
    int s0 = ofs[wave], s1 = ofs[wave + 1];
    float4 acc = make_float4(0.f, 0.f, 0.f, 0.f);
    for (int e = s0; e < s1; e++) {
        const float4* xr = (const float4*)(x + (size_t)perm[e] * 256);
        float4 v = xr[lane];
        acc.x += v.x; acc.y += v.y; acc.z += v.z; acc.w += v.w;
    }
    float inv = 1.0f / fmaxf((float)(s1 - s0), 1.0f);
    acc.x *= inv; acc.y *= inv; acc.z *= inv; acc.w *= inv;
    ((float4*)(agg + (size_t)wave * 256))[lane] = acc;
}

// ---------- weight prep ----------
__global__ void prep_w0(const float* __restrict__ Wl, const float* __restrict__ Wr,
                        unsigned short* __restrict__ Wt) {
    int idx = blockIdx.x * 256 + threadIdx.x;     // 256 n x 256 k
    int n = idx >> 8, k = idx & 255;
    float v = 0.f;
    if (k < 100) v = Wl[k * 256 + n];
    else if (k >= 128 && k < 228) v = Wr[(k - 128) * 256 + n];
    Wt[idx] = f2bf(v);
}
__global__ void prep_w1(const float* __restrict__ Wl, const float* __restrict__ Wr,
                        unsigned short* __restrict__ Wt) {
    int idx = blockIdx.x * 256 + threadIdx.x;     // 256 n x 512 k
    int n = idx >> 9, k = idx & 511;
    float v = (k < 256) ? Wl[k * 256 + n] : Wr[(k - 256) * 256 + n];
    Wt[idx] = f2bf(v);
}

// ---------- bf16 MFMA GEMM (layers 0,1) ----------
template <int OUT_BF16, int RELU>
__global__ __launch_bounds__(256) void mfma_gemm(const unsigned short* __restrict__ A,
                                                 const unsigned short* __restrict__ Wt,
                                                 const float* __restrict__ bias,
                                                 void* __restrict__ outp,
                                                 int M, int N, int K) {
    __shared__ unsigned short As[128][40];
    __shared__ unsigned short Bs[128][40];
    int tid = threadIdx.x;
    int lane = tid & 63, wid = tid >> 6;
    int wm = (wid & 1) * 64, wn = (wid >> 1) * 64;
    int bm = blockIdx.y * 128, bn = blockIdx.x * 128;

    f32x4_t acc[4][4];
#pragma unroll
    for (int i = 0; i < 4; i++)
#pragma unroll
        for (int j = 0; j < 4; j++)
#pragma unroll
            for (int r = 0; r < 4; r++) acc[i][j][r] = 0.f;

    int r0 = lane & 15, kg = lane >> 4;

    for (int k0 = 0; k0 < K; k0 += 32) {
        {
            int c = tid;
            int row = c >> 2, k8 = (c & 3) << 3;
            *reinterpret_cast<int4*>(&As[row][k8]) =
                *reinterpret_cast<const int4*>(&A[(size_t)(bm + row) * K + k0 + k8]);
            c = tid + 256;
            row = c >> 2; k8 = (c & 3) << 3;
            *reinterpret_cast<int4*>(&As[row][k8]) =
                *reinterpret_cast<const int4*>(&A[(size_t)(bm + row) * K + k0 + k8]);
        }
        {
            int c = tid;
            int row = c >> 2, k8 = (c & 3) << 3;
            *reinterpret_cast<int4*>(&Bs[row][k8]) =
                *reinterpret_cast<const int4*>(&Wt[(size_t)(bn + row) * K + k0 + k8]);
            c = tid + 256;
            row = c >> 2; k8 = (c & 3) << 3;
            *reinterpret_cast<int4*>(&Bs[row][k8]) =
                *reinterpret_cast<const int4*>(&Wt[(size_t)(bn + row) * K + k0 + k8]);
        }
        __syncthreads();

        bf16x8_t af[4], bfv[4];
#pragma unroll
        for (int mi = 0; mi < 4; mi++)
            af[mi] = *reinterpret_cast<const bf16x8_t*>(&As[wm + mi * 16 + r0][kg * 8]);
#pragma unroll
        for (int ni = 0; ni < 4; ni++)
            bfv[ni] = *reinterpret_cast<const bf16x8_t*>(&Bs[wn + ni * 16 + r0][kg * 8]);
#pragma unroll
        for (int mi = 0; mi < 4; mi++)
#pragma unroll
            for (int ni = 0; ni < 4; ni++)
                acc[mi][ni] = __builtin_amdgcn_mfma_f32_16x16x32_bf16(af[mi], bfv[ni], acc[mi][ni], 0, 0, 0);
        __syncthreads();
    }

    int cc = lane & 15, rr = (lane >> 4) * 4;
#pragma unroll
    for (int mi = 0; mi < 4; mi++) {
#pragma unroll
        for (int ni = 0; ni < 4; ni++) {
            int col = bn + wn + ni * 16 + cc;
            float b = bias[col];
#pragma unroll
            for (int j = 0; j < 4; j++) {
                int row = bm + wm + mi * 16 + rr + j;
                float v = acc[mi][ni][j] + b;
                if (RELU) v = fmaxf(v, 0.f);
                if (OUT_BF16)
                    ((unsigned short*)outp)[(size_t)row * N + col] = f2bf(v);
                else
                    ((float*)outp)[(size_t)row * N + col] = v;
            }
        }
    }
}

// ---------- layer-2: fp32 dual GEMM with fused log_softmax ----------
// M=1024, N=47 (<64, one column-tile), K1=K2=256. Each block: 64 rows x full N.
__global__ __launch_bounds__(256) void gemm2_fused(const float* __restrict__ A1, const float* __restrict__ W1, int K1,
                                                   const float* __restrict__ A2, const float* __restrict__ W2, int K2,
                                                   const float* __restrict__ bias, float* __restrict__ out,
                                                   int M, int N) {
    __shared__ float As[16][65];
    __shared__ float Bs[16][64];
    int tid = threadIdx.x;
    int tx = tid & 15, ty = tid >> 4;
    int bm = blockIdx.y * 64;
    float acc[4][4] = {};
    for (int pass = 0; pass < 2; ++pass) {
        const float* A = pass ? A2 : A1;
        const float* W = pass ? W2 : W1;
        int K = pass ? K2 : K1;
        for (int k0 = 0; k0 < K; k0 += 16) {
#pragma unroll
            for (int i = 0; i < 4; i++) {
                int L = i * 256 + tid;
                int m = L >> 4, k = L & 15;
                int gm = bm + m, gk = k0 + k;
                float v = 0.f;
                if (gm < M && gk < K) v = A[(size_t)gm * K + gk];
                As[k][m] = v;
            }
#pragma unroll
            for (int i = 0; i < 4; i++) {
                int L = i * 256 + tid;
                int n = L & 63, k = L >> 6;
                int gk = k0 + k;
                float v = 0.f;
                if (gk < K && n < N) v = W[(size_t)gk * N + n];
                Bs[k][n] = v;
            }
            __syncthreads();
#pragma unroll
            for (int k = 0; k < 16; k++) {
                float a[4], b[4];
#pragma unroll
                for (int i = 0; i < 4; i++) a[i] = As[k][ty * 4 + i];
#pragma unroll
                for (int j = 0; j < 4; j++) b[j] = Bs[k][tx * 4 + j];
#pragma unroll
                for (int i = 0; i < 4; i++)
#pragma unroll
                    for (int j = 0; j < 4; j++) acc[i][j] += a[i] * b[j];
            }
            __syncthreads();
        }
    }
    // fused bias + log_softmax per row (row spread over the 16 lanes sharing ty)
#pragma unroll
    for (int i = 0; i < 4; i++) {
        int gm = bm + ty * 4 + i;
        float vals[4];
        float vmax = -1e30f;
#pragma unroll
        for (int j = 0; j < 4; j++) {
            int gn = tx * 4 + j;
            vals[j] = (gn < N) ? acc[i][j] + bias[gn] : -1e30f;
            vmax = fmaxf(vmax, vals[j]);
        }
#pragma unroll
        for (int o = 1; o < 16; o <<= 1) vmax = fmaxf(vmax, __shfl_xor(vmax, o));
        float se = 0.f;
#pragma unroll
        for (int j = 0; j < 4; j++) {
            int gn = tx * 4 + j;
            if (gn < N) se += expf(vals[j] - vmax);
        }
#pragma unroll
        for (int o = 1; o < 16; o <<= 1) se += __shfl_xor(se, o);
        float ls = logf(se);
#pragma unroll
        for (int j = 0; j < 4; j++) {
            int gn = tx * 4 + j;
            if (gn < N && gm < M) out[(size_t)gm * N + gn] = vals[j] - vmax - ls;
        }
    }
}

extern "C" void kernel_launch(void* const* d_in, const int* in_sizes, int n_in,
                              void* d_out, int out_size, void* d_ws, size_t ws_size,
                              hipStream_t stream) {
    const float* x   = (const float*)d_in[0];
    const int* src0  = (const int*)d_in[1];
    const int* dst0  = (const int*)d_in[2];
    const int* src1  = (const int*)d_in[3];
    const int* dst1  = (const int*)d_in[4];
    const int* src2  = (const int*)d_in[5];
    const int* dst2  = (const int*)d_in[6];
    const float* Wl0 = (const float*)d_in[7];
    const float* bl0 = (const float*)d_in[8];
    const float* Wr0 = (const float*)d_in[9];
    const float* Wl1 = (const float*)d_in[10];
    const float* bl1 = (const float*)d_in[11];
    const float* Wr1 = (const float*)d_in[12];
    const float* Wl2 = (const float*)d_in[13];
    const float* bl2 = (const float*)d_in[14];
    const float* Wr2 = (const float*)d_in[15];
    float* out = (float*)d_out;

    // ---- workspace layout ----
    char* p = (char*)d_ws;
    auto alloc = [&](size_t bytes) { char* r = p; p += (bytes + 255) & ~(size_t)255; return r; };
    unsigned short* Ab0 = (unsigned short*)alloc((size_t)NN1 * 256 * 2);
    unsigned short* h1  = (unsigned short*)alloc((size_t)NN1 * 256 * 2);
    unsigned short* Ab1 = (unsigned short*)alloc((size_t)NN2 * 512 * 2);
    float* h2    = (float*)alloc((size_t)NN2 * 256 * 4);
    float* agg2  = (float*)alloc((size_t)NN3 * 256 * 4);
    unsigned short* Wt0 = (unsigned short*)alloc(256 * 256 * 2);
    unsigned short* Wt1 = (unsigned short*)alloc(256 * 512 * 2);
    int* cnt    = (int*)alloc((size_t)NTOT * 4);
    int* ofs    = (int*)alloc((size_t)(NTOT + 1) * 4);
    int* cursor = (int*)alloc((size_t)(NTOT + 1) * 4);
    int* sums   = (int*)alloc(128 * 4);
    int* perm   = (int*)alloc((size_t)ETOT * 4);

    // ---- weight prep + fused CSR build (independent of layer compute) ----
    prep_w0<<<256, 256, 0, stream>>>(Wl0, Wr0, Wt0);
    prep_w1<<<512, 256, 0, stream>>>(Wl1, Wr1, Wt1);
    hipMemsetAsync(cnt, 0, (size_t)NTOT * 4, stream);
    count_all<<<cdiv(ETOT, 256), 256, 0, stream>>>(dst0, dst1, dst2, cnt);
    int nb = cdiv(NTOT, 1024);   // 73
    scan1<<<nb, 1024, 0, stream>>>(cnt, NTOT, ofs, sums);
    scan2<<<1, 128, 0, stream>>>(sums, nb, ofs, NTOT);
    scan3<<<cdiv(NTOT, 256), 256, 0, stream>>>(sums, NTOT, ofs, cursor);
    scatter_all<<<cdiv(ETOT, 256), 256, 0, stream>>>(src0, dst0, src1, dst1, src2, dst2, cursor, perm);

    // ---- layer 0 ----
    agg0_kernel<<<cdiv(NN1 * 64, 256), 256, 0, stream>>>(x, perm, ofs, Ab0, NN1);
    {
        dim3 grid(256 / 128, NN1 / 128);
        mfma_gemm<1, 1><<<grid, 256, 0, stream>>>(Ab0, Wt0, bl0, h1, NN1, 256, 256);
    }

    // ---- layer 1 ----
    agg1_kernel<<<cdiv(NN2 * 64, 256), 256, 0, stream>>>(h1, perm, ofs + NN1, Ab1, NN2);
    {
        dim3 grid(256 / 128, NN2 / 128);
        mfma_gemm<0, 1><<<grid, 256, 0, stream>>>(Ab1, Wt1, bl1, h2, NN2, 256, 512);
    }

    // ---- layer 2 (fp32, fused log_softmax) ----
    agg_vec4_256<<<cdiv(NN3 * 64, 256), 256, 0, stream>>>(h2, perm, ofs + NN1 + NN2, agg2, NN3);
    {
        dim3 grid(1, cdiv(NN3, 64));
        gemm2_fused<<<grid, 256, 0, stream>>>(agg2, Wl2, 256, h2, Wr2, 256, bl2, out, NN3, 47);
    }
}

// Round 4
// 298.842 us; speedup vs baseline: 2.5739x; 1.0341x over previous
//
#include <hip/hip_runtime.h>
#include <math.h>

// ---------- problem constants ----------
constexpr int NN1 = 65536, NN2 = 8192, NN3 = 1024;
constexpr int E0 = 655360, E1 = 81920, E2 = 10240;
constexpr int ETOT = E0 + E1 + E2;           // 747520
constexpr int NTOT = NN1 + NN2 + NN3;        // 74752

static inline int cdiv(int a, int b) { return (a + b - 1) / b; }

typedef __bf16 bf16x8_t __attribute__((ext_vector_type(8)));
typedef float f32x4_t __attribute__((ext_vector_type(4)));

__device__ __forceinline__ unsigned short f2bf(float f) {
    union { float f; unsigned int u; } v; v.f = f;
    unsigned int r = v.u + 0x7fffu + ((v.u >> 16) & 1u);
    return (unsigned short)(r >> 16);
}
__device__ __forceinline__ float bf2f(unsigned short h) {
    union { unsigned int u; float f; } v; v.u = ((unsigned int)h) << 16;
    return v.f;
}

// ---------- fused CSR build ----------
__global__ void count_all(const int* __restrict__ dst0, const int* __restrict__ dst1,
                          const int* __restrict__ dst2, int* __restrict__ cnt) {
    int i = blockIdx.x * 256 + threadIdx.x;
    if (i < E0) atomicAdd(&cnt[dst0[i]], 1);
    else if (i < E0 + E1) atomicAdd(&cnt[NN1 + dst1[i - E0]], 1);
    else if (i < ETOT) atomicAdd(&cnt[NN1 + NN2 + dst2[i - E0 - E1]], 1);
}

// phase 1: per-1024-chunk exclusive scan, chunk sums out
__global__ __launch_bounds__(1024) void scan1(const int* __restrict__ cnt, int n,
                                              int* __restrict__ ofs, int* __restrict__ sums) {
    __shared__ int s[1024];
    int i = blockIdx.x * 1024 + threadIdx.x;
    int v = (i < n) ? cnt[i] : 0;
    s[threadIdx.x] = v;
    __syncthreads();
    for (int off = 1; off < 1024; off <<= 1) {
        int t = (threadIdx.x >= off) ? s[threadIdx.x - off] : 0;
        __syncthreads();
        s[threadIdx.x] += t;
        __syncthreads();
    }
    if (i < n) ofs[i] = s[threadIdx.x] - v;
    if (threadIdx.x == 1023) sums[blockIdx.x] = s[1023];
}

// phase 2 (merged): each 256-thread block lies inside one 1024-chunk; wave 0
// computes the chunk prefix over sums[] (<=73 entries), then all add.
__global__ void scan3(const int* __restrict__ sums, int n,
                      int* __restrict__ ofs, int* __restrict__ cursor) {
    __shared__ int pref_s;
    int c = (blockIdx.x * 256) >> 10;   // chunk index of this block
    if (threadIdx.x < 64) {
        int v = 0;
        for (int j = threadIdx.x; j < c; j += 64) v += sums[j];
        for (int o = 32; o; o >>= 1) v += __shfl_down(v, o);
        if (threadIdx.x == 0) pref_s = v;
    }
    __syncthreads();
    int i = blockIdx.x * 256 + threadIdx.x;
    if (i < n) {
        int v = ofs[i] + pref_s;
        ofs[i] = v;
        cursor[i] = v;
    }
    if (blockIdx.x == 0 && threadIdx.x == 0) ofs[n] = ETOT;  // grand total is static
}

__global__ void scatter_all(const int* __restrict__ src0, const int* __restrict__ dst0,
                            const int* __restrict__ src1, const int* __restrict__ dst1,
                            const int* __restrict__ src2, const int* __restrict__ dst2,
                            int* __restrict__ cursor, int* __restrict__ perm) {
    int i = blockIdx.x * 256 + threadIdx.x;
    if (i < E0) {
        int p = atomicAdd(&cursor[dst0[i]], 1);
        perm[p] = src0[i];
    } else if (i < E0 + E1) {
        int j = i - E0;
        int p = atomicAdd(&cursor[NN1 + dst1[j]], 1);
        perm[p] = src1[j];
    } else if (i < ETOT) {
        int j = i - E0 - E1;
        int p = atomicAdd(&cursor[NN1 + NN2 + dst2[j]], 1);
        perm[p] = src2[j];
    }
}

// ---------- layer-0 aggregate ----------
// Row = 25 float4. Dual lane groups (lanes 0-31 even edges, 32-63 odd), unroll x4
// => 8 edges (3.2 KB) in flight per wave. Output row (K=224):
// [agg bf16 0..99 | x_dst bf16 100..199 | zero 200..223].
__global__ void agg0_kernel(const float* __restrict__ x, const int* __restrict__ perm,
                            const int* __restrict__ ofs, unsigned short* __restrict__ Ab, int nrows) {
    int wave = (blockIdx.x * blockDim.x + threadIdx.x) >> 6;
    int lane = threadIdx.x & 63;
    if (wave >= nrows) return;
    int g = lane >> 5, l5 = lane & 31;
    bool act = l5 < 25;
    int s0 = ofs[wave], s1 = ofs[wave + 1];
    float inv = 1.0f / fmaxf((float)(s1 - s0), 1.0f);
    f32x4_t A0 = {0.f, 0.f, 0.f, 0.f}, A1 = A0, A2 = A0, A3 = A0;
    int e = s0;
    for (; e + 8 <= s1; e += 8) {
        int p0 = perm[e + 0 + g];
        int p1 = perm[e + 2 + g];
        int p2 = perm[e + 4 + g];
        int p3 = perm[e + 6 + g];
        if (act) {
            A0 += *reinterpret_cast<const f32x4_t*>(x + (size_t)p0 * 100 + l5 * 4);
            A1 += *reinterpret_cast<const f32x4_t*>(x + (size_t)p1 * 100 + l5 * 4);
            A2 += *reinterpret_cast<const f32x4_t*>(x + (size_t)p2 * 100 + l5 * 4);
            A3 += *reinterpret_cast<const f32x4_t*>(x + (size_t)p3 * 100 + l5 * 4);
        }
    }
    for (; e < s1; e += 2) {
        int idx = e + g;
        if (idx < s1 && act)
            A0 += *reinterpret_cast<const f32x4_t*>(x + (size_t)perm[idx] * 100 + l5 * 4);
    }
    f32x4_t a = (A0 + A1) + (A2 + A3);
#pragma unroll
    for (int c = 0; c < 4; c++) a[c] += __shfl_xor(a[c], 32);
    unsigned short* row = Ab + (size_t)wave * 224;
    if (lane < 25) {
        ushort4 o;
        o.x = f2bf(a[0] * inv); o.y = f2bf(a[1] * inv);
        o.z = f2bf(a[2] * inv); o.w = f2bf(a[3] * inv);
        *reinterpret_cast<ushort4*>(row + lane * 4) = o;
        f32x4_t d = *reinterpret_cast<const f32x4_t*>(x + (size_t)wave * 100 + lane * 4);
        ushort4 od;
        od.x = f2bf(d[0]); od.y = f2bf(d[1]); od.z = f2bf(d[2]); od.w = f2bf(d[3]);
        *reinterpret_cast<ushort4*>(row + 100 + lane * 4) = od;
    } else if (lane < 31) {
        *reinterpret_cast<ushort4*>(row + 100 + lane * 4) = make_ushort4(0, 0, 0, 0);  // 200..223
    }
}

// ---------- layer-1 aggregate: h1 bf16 (D=256), unroll x4 ----------
__global__ void agg1_kernel(const unsigned short* __restrict__ h, const int* __restrict__ perm,
                            const int* __restrict__ ofs, unsigned short* __restrict__ Ab, int nrows) {
    int wave = (blockIdx.x * blockDim.x + threadIdx.x) >> 6;
    int lane = threadIdx.x & 63;
    if (wave >= nrows) return;
    int s0 = ofs[wave], s1 = ofs[wave + 1];
    float inv = 1.0f / fmaxf((float)(s1 - s0), 1.0f);
    float acc[4][4] = {};
    int e = s0;
    for (; e + 4 <= s1; e += 4) {
        ushort4 v[4];
#pragma unroll
        for (int u = 0; u < 4; u++)
            v[u] = *reinterpret_cast<const ushort4*>(h + (size_t)perm[e + u] * 256 + lane * 4);
#pragma unroll
        for (int u = 0; u < 4; u++) {
            acc[u][0] += bf2f(v[u].x); acc[u][1] += bf2f(v[u].y);
            acc[u][2] += bf2f(v[u].z); acc[u][3] += bf2f(v[u].w);
        }
    }
    for (; e < s1; e++) {
        ushort4 v = *reinterpret_cast<const ushort4*>(h + (size_t)perm[e] * 256 + lane * 4);
        acc[0][0] += bf2f(v.x); acc[0][1] += bf2f(v.y);
        acc[0][2] += bf2f(v.z); acc[0][3] += bf2f(v.w);
    }
    ushort4 o;
    o.x = f2bf((acc[0][0] + acc[1][0] + acc[2][0] + acc[3][0]) * inv);
    o.y = f2bf((acc[0][1] + acc[1][1] + acc[2][1] + acc[3][1]) * inv);
    o.z = f2bf((acc[0][2] + acc[1][2] + acc[2][2] + acc[3][2]) * inv);
    o.w = f2bf((acc[0][3] + acc[1][3] + acc[2][3] + acc[3][3]) * inv);
    *reinterpret_cast<ushort4*>(Ab + (size_t)wave * 512 + lane * 4) = o;
    *reinterpret_cast<ushort4*>(Ab + (size_t)wave * 512 + 256 + lane * 4) =
        *reinterpret_cast<const ushort4*>(h + (size_t)wave * 256 + lane * 4);
}

// ---------- layer-2 aggregate: h2 fp32 (D=256) ----------
__global__ void agg_vec4_256(const float* __restrict__ x, const int* __restrict__ perm,
                             const int* __restrict__ ofs, float* __restrict__ agg, int nrows) {
    int wave = (blockIdx.x * blockDim.x + threadIdx.x) >> 6;
    int lane = threadIdx.x & 63;
    if (wave >= nrows) return;
    int s0 = ofs[wave], s1 = ofs[wave + 1];
    float4 acc = make_float4(0.f, 0.f, 0.f, 0.f);
    for (int e = s0; e < s1; e++) {
        const float4* xr = (const float4*)(x + (size_t)perm[e] * 256);
        float4 v = xr[lane];
        acc.x += v.x; acc.y += v.y; acc.z += v.z; acc.w += v.w;
    }
    float inv = 1.0f / fmaxf((float)(s1 - s0), 1.0f);
    acc.x *= inv; acc.y *= inv; acc.z *= inv; acc.w *= inv;
    ((float4*)(agg + (size_t)wave * 256))[lane] = acc;
}

// ---------- merged weight prep ----------
// blocks 0..255: Wt0[n=blk][k=tid<224]   (K0=224: [Wl 0..99 | Wr 100..199 | 0 200..223])
// blocks 256..767: Wt1 flat (256n x 512k: [Wl 256 | Wr 256])
__global__ void prep_w(const float* __restrict__ Wl0, const float* __restrict__ Wr0,
                       unsigned short* __restrict__ Wt0,
                       const float* __restrict__ Wl1, const float* __restrict__ Wr1,
                       unsigned short* __restrict__ Wt1) {
    int b = blockIdx.x;
    if (b < 256) {
        int n = b, k = threadIdx.x;
        if (k < 224) {
            float v = (k < 100) ? Wl0[k * 256 + n] : (k < 200 ? Wr0[(k - 100) * 256 + n] : 0.f);
            Wt0[n * 224 + k] = f2bf(v);
        }
    } else {
        int idx = (b - 256) * 256 + threadIdx.x;
        int n = idx >> 9, k = idx & 511;
        float v = (k < 256) ? Wl1[k * 256 + n] : Wr1[(k - 256) * 256 + n];
        Wt1[idx] = f2bf(v);
    }
}

// ---------- bf16 MFMA GEMM (layers 0,1); K % 32 == 0 ----------
template <int OUT_BF16, int RELU>
__global__ __launch_bounds__(256) void mfma_gemm(const unsigned short* __restrict__ A,
                                                 const unsigned short* __restrict__ Wt,
                                                 const float* __restrict__ bias,
                                                 void* __restrict__ outp,
                                                 int M, int N, int K) {
    __shared__ unsigned short As[128][40];
    __shared__ unsigned short Bs[128][40];
    int tid = threadIdx.x;
    int lane = tid & 63, wid = tid >> 6;
    int wm = (wid & 1) * 64, wn = (wid >> 1) * 64;
    int bm = blockIdx.y * 128, bn = blockIdx.x * 128;

    f32x4_t acc[4][4];
#pragma unroll
    for (int i = 0; i < 4; i++)
#pragma unroll
        for (int j = 0; j < 4; j++)
#pragma unroll
            for (int r = 0; r < 4; r++) acc[i][j][r] = 0.f;

    int r0 = lane & 15, kg = lane >> 4;

    for (int k0 = 0; k0 < K; k0 += 32) {
        {
            int c = tid;
            int row = c >> 2, k8 = (c & 3) << 3;
            *reinterpret_cast<int4*>(&As[row][k8]) =
                *reinterpret_cast<const int4*>(&A[(size_t)(bm + row) * K + k0 + k8]);
            c = tid + 256;
            row = c >> 2; k8 = (c & 3) << 3;
            *reinterpret_cast<int4*>(&As[row][k8]) =
                *reinterpret_cast<const int4*>(&A[(size_t)(bm + row) * K + k0 + k8]);
        }
        {
            int c = tid;
            int row = c >> 2, k8 = (c & 3) << 3;
            *reinterpret_cast<int4*>(&Bs[row][k8]) =
                *reinterpret_cast<const int4*>(&Wt[(size_t)(bn + row) * K + k0 + k8]);
            c = tid + 256;
            row = c >> 2; k8 = (c & 3) << 3;
            *reinterpret_cast<int4*>(&Bs[row][k8]) =
                *reinterpret_cast<const int4*>(&Wt[(size_t)(bn + row) * K + k0 + k8]);
        }
        __syncthreads();

        bf16x8_t af[4], bfv[4];
#pragma unroll
        for (int mi = 0; mi < 4; mi++)
            af[mi] = *reinterpret_cast<const bf16x8_t*>(&As[wm + mi * 16 + r0][kg * 8]);
#pragma unroll
        for (int ni = 0; ni < 4; ni++)
            bfv[ni] = *reinterpret_cast<const bf16x8_t*>(&Bs[wn + ni * 16 + r0][kg * 8]);
#pragma unroll
        for (int mi = 0; mi < 4; mi++)
#pragma unroll
            for (int ni = 0; ni < 4; ni++)
                acc[mi][ni] = __builtin_amdgcn_mfma_f32_16x16x32_bf16(af[mi], bfv[ni], acc[mi][ni], 0, 0, 0);
        __syncthreads();
    }

    int cc = lane & 15, rr = (lane >> 4) * 4;
#pragma unroll
    for (int mi = 0; mi < 4; mi++) {
#pragma unroll
        for (int ni = 0; ni < 4; ni++) {
            int col = bn + wn + ni * 16 + cc;
            float b = bias[col];
#pragma unroll
            for (int j = 0; j < 4; j++) {
                int row = bm + wm + mi * 16 + rr + j;
                float v = acc[mi][ni][j] + b;
                if (RELU) v = fmaxf(v, 0.f);
                if (OUT_BF16)
                    ((unsigned short*)outp)[(size_t)row * N + col] = f2bf(v);
                else
                    ((float*)outp)[(size_t)row * N + col] = v;
            }
        }
    }
}

// ---------- layer-2: fp32 dual GEMM with fused log_softmax ----------
__global__ __launch_bounds__(256) void gemm2_fused(const float* __restrict__ A1, const float* __restrict__ W1, int K1,
                                                   const float* __restrict__ A2, const float* __restrict__ W2, int K2,
                                                   const float* __restrict__ bias, float* __restrict__ out,
                                                   int M, int N) {
    __shared__ float As[16][65];
    __shared__ float Bs[16][64];
    int tid = threadIdx.x;
    int tx = tid & 15, ty = tid >> 4;
    int bm = blockIdx.y * 64;
    float acc[4][4] = {};
    for (int pass = 0; pass < 2; ++pass) {
        const float* A = pass ? A2 : A1;
        const float* W = pass ? W2 : W1;
        int K = pass ? K2 : K1;
        for (int k0 = 0; k0 < K; k0 += 16) {
#pragma unroll
            for (int i = 0; i < 4; i++) {
                int L = i * 256 + tid;
                int m = L >> 4, k = L & 15;
                int gm = bm + m, gk = k0 + k;
                float v = 0.f;
                if (gm < M && gk < K) v = A[(size_t)gm * K + gk];
                As[k][m] = v;
            }
#pragma unroll
            for (int i = 0; i < 4; i++) {
                int L = i * 256 + tid;
                int n = L & 63, k = L >> 6;
                int gk = k0 + k;
                float v = 0.f;
                if (gk < K && n < N) v = W[(size_t)gk * N + n];
                Bs[k][n] = v;
            }
            __syncthreads();
#pragma unroll
            for (int k = 0; k < 16; k++) {
                float a[4], b[4];
#pragma unroll
                for (int i = 0; i < 4; i++) a[i] = As[k][ty * 4 + i];
#pragma unroll
                for (int j = 0; j < 4; j++) b[j] = Bs[k][tx * 4 + j];
#pragma unroll
                for (int i = 0; i < 4; i++)
#pragma unroll
                    for (int j = 0; j < 4; j++) acc[i][j] += a[i] * b[j];
            }
            __syncthreads();
        }
    }
#pragma unroll
    for (int i = 0; i < 4; i++) {
        int gm = bm + ty * 4 + i;
        float vals[4];
        float vmax = -1e30f;
#pragma unroll
        for (int j = 0; j < 4; j++) {
            int gn = tx * 4 + j;
            vals[j] = (gn < N) ? acc[i][j] + bias[gn] : -1e30f;
            vmax = fmaxf(vmax, vals[j]);
        }
#pragma unroll
        for (int o = 1; o < 16; o <<= 1) vmax = fmaxf(vmax, __shfl_xor(vmax, o));
        float se = 0.f;
#pragma unroll
        for (int j = 0; j < 4; j++) {
            int gn = tx * 4 + j;
            if (gn < N) se += expf(vals[j] - vmax);
        }
#pragma unroll
        for (int o = 1; o < 16; o <<= 1) se += __shfl_xor(se, o);
        float ls = logf(se);
#pragma unroll
        for (int j = 0; j < 4; j++) {
            int gn = tx * 4 + j;
            if (gn < N && gm < M) out[(size_t)gm * N + gn] = vals[j] - vmax - ls;
        }
    }
}

extern "C" void kernel_launch(void* const* d_in, const int* in_sizes, int n_in,
                              void* d_out, int out_size, void* d_ws, size_t ws_size,
                              hipStream_t stream) {
    const float* x   = (const float*)d_in[0];
    const int* src0  = (const int*)d_in[1];
    const int* dst0  = (const int*)d_in[2];
    const int* src1  = (const int*)d_in[3];
    const int* dst1  = (const int*)d_in[4];
    const int* src2  = (const int*)d_in[5];
    const int* dst2  = (const int*)d_in[6];
    const float* Wl0 = (const float*)d_in[7];
    const float* bl0 = (const float*)d_in[8];
    const float* Wr0 = (const float*)d_in[9];
    const float* Wl1 = (const float*)d_in[10];
    const float* bl1 = (const float*)d_in[11];
    const float* Wr1 = (const float*)d_in[12];
    const float* Wl2 = (const float*)d_in[13];
    const float* bl2 = (const float*)d_in[14];
    const float* Wr2 = (const float*)d_in[15];
    float* out = (float*)d_out;

    // ---- workspace layout ----
    char* p = (char*)d_ws;
    auto alloc = [&](size_t bytes) { char* r = p; p += (bytes + 255) & ~(size_t)255; return r; };
    unsigned short* Ab0 = (unsigned short*)alloc((size_t)NN1 * 224 * 2);
    unsigned short* h1  = (unsigned short*)alloc((size_t)NN1 * 256 * 2);
    unsigned short* Ab1 = (unsigned short*)alloc((size_t)NN2 * 512 * 2);
    float* h2    = (float*)alloc((size_t)NN2 * 256 * 4);
    float* agg2  = (float*)alloc((size_t)NN3 * 256 * 4);
    unsigned short* Wt0 = (unsigned short*)alloc(256 * 224 * 2);
    unsigned short* Wt1 = (unsigned short*)alloc(256 * 512 * 2);
    int* cnt    = (int*)alloc((size_t)NTOT * 4);
    int* ofs    = (int*)alloc((size_t)(NTOT + 1) * 4);
    int* cursor = (int*)alloc((size_t)(NTOT + 1) * 4);
    int* sums   = (int*)alloc(128 * 4);
    int* perm   = (int*)alloc((size_t)ETOT * 4);

    // ---- weight prep + fused CSR build ----
    prep_w<<<768, 256, 0, stream>>>(Wl0, Wr0, Wt0, Wl1, Wr1, Wt1);
    hipMemsetAsync(cnt, 0, (size_t)NTOT * 4, stream);
    count_all<<<cdiv(ETOT, 256), 256, 0, stream>>>(dst0, dst1, dst2, cnt);
    int nb = cdiv(NTOT, 1024);   // 73
    scan1<<<nb, 1024, 0, stream>>>(cnt, NTOT, ofs, sums);
    scan3<<<cdiv(NTOT, 256), 256, 0, stream>>>(sums, NTOT, ofs, cursor);
    scatter_all<<<cdiv(ETOT, 256), 256, 0, stream>>>(src0, dst0, src1, dst1, src2, dst2, cursor, perm);

    // ---- layer 0 (K=224) ----
    agg0_kernel<<<cdiv(NN1 * 64, 256), 256, 0, stream>>>(x, perm, ofs, Ab0, NN1);
    {
        dim3 grid(256 / 128, NN1 / 128);
        mfma_gemm<1, 1><<<grid, 256, 0, stream>>>(Ab0, Wt0, bl0, h1, NN1, 256, 224);
    }

    // ---- layer 1 (K=512) ----
    agg1_kernel<<<cdiv(NN2 * 64, 256), 256, 0, stream>>>(h1, perm, ofs + NN1, Ab1, NN2);
    {
        dim3 grid(256 / 128, NN2 / 128);
        mfma_gemm<0, 1><<<grid, 256, 0, stream>>>(Ab1, Wt1, bl1, h2, NN2, 256, 512);
    }

    // ---- layer 2 (fp32, fused log_softmax) ----
    agg_vec4_256<<<cdiv(NN3 * 64, 256), 256, 0, stream>>>(h2, perm, ofs + NN1 + NN2, agg2, NN3);
    {
        dim3 grid(1, cdiv(NN3, 64));
        gemm2_fused<<<grid, 256, 0, stream>>>(agg2, Wl2, 256, h2, Wr2, 256, bl2, out, NN3, 47);
    }
}

// Round 5
// 291.429 us; speedup vs baseline: 2.6394x; 1.0254x over previous
//
#include <hip/hip_runtime.h>
#include <math.h>

// ---------- problem constants ----------
constexpr int NN1 = 65536, NN2 = 8192, NN3 = 1024;
constexpr int E0 = 655360, E1 = 81920, E2 = 10240;
constexpr int ETOT = E0 + E1 + E2;           // 747520
constexpr int NTOT = NN1 + NN2 + NN3;        // 74752

static inline int cdiv(int a, int b) { return (a + b - 1) / b; }

typedef __bf16 bf16x8_t __attribute__((ext_vector_type(8)));
typedef float f32x4_t __attribute__((ext_vector_type(4)));

__device__ __forceinline__ unsigned short f2bf(float f) {
    union { float f; unsigned int u; } v; v.f = f;
    unsigned int r = v.u + 0x7fffu + ((v.u >> 16) & 1u);
    return (unsigned short)(r >> 16);
}
__device__ __forceinline__ float bf2f(unsigned short h) {
    union { unsigned int u; float f; } v; v.u = ((unsigned int)h) << 16;
    return v.f;
}

// ---------- fused CSR build ----------
__global__ void count_all(const int* __restrict__ dst0, const int* __restrict__ dst1,
                          const int* __restrict__ dst2, int* __restrict__ cnt) {
    int i = blockIdx.x * 256 + threadIdx.x;
    if (i < E0) atomicAdd(&cnt[dst0[i]], 1);
    else if (i < E0 + E1) atomicAdd(&cnt[NN1 + dst1[i - E0]], 1);
    else if (i < ETOT) atomicAdd(&cnt[NN1 + NN2 + dst2[i - E0 - E1]], 1);
}

__global__ __launch_bounds__(1024) void scan1(const int* __restrict__ cnt, int n,
                                              int* __restrict__ ofs, int* __restrict__ sums) {
    __shared__ int s[1024];
    int i = blockIdx.x * 1024 + threadIdx.x;
    int v = (i < n) ? cnt[i] : 0;
    s[threadIdx.x] = v;
    __syncthreads();
    for (int off = 1; off < 1024; off <<= 1) {
        int t = (threadIdx.x >= off) ? s[threadIdx.x - off] : 0;
        __syncthreads();
        s[threadIdx.x] += t;
        __syncthreads();
    }
    if (i < n) ofs[i] = s[threadIdx.x] - v;
    if (threadIdx.x == 1023) sums[blockIdx.x] = s[1023];
}

// add chunk-prefix (computed by wave 0 of each block over <=73 sums) and fill cursor
__global__ void scan3(const int* __restrict__ sums, int n,
                      int* __restrict__ ofs, int* __restrict__ cursor) {
    __shared__ int pref_s;
    int c = (blockIdx.x * 256) >> 10;
    if (threadIdx.x < 64) {
        int v = 0;
        for (int j = threadIdx.x; j < c; j += 64) v += sums[j];
        for (int o = 32; o; o >>= 1) v += __shfl_down(v, o);
        if (threadIdx.x == 0) pref_s = v;
    }
    __syncthreads();
    int i = blockIdx.x * 256 + threadIdx.x;
    if (i < n) {
        int v = ofs[i] + pref_s;
        ofs[i] = v;
        cursor[i] = v;
    }
    if (blockIdx.x == 0 && threadIdx.x == 0) ofs[n] = ETOT;
}

__global__ void scatter_all(const int* __restrict__ src0, const int* __restrict__ dst0,
                            const int* __restrict__ src1, const int* __restrict__ dst1,
                            const int* __restrict__ src2, const int* __restrict__ dst2,
                            int* __restrict__ cursor, int* __restrict__ perm) {
    int i = blockIdx.x * 256 + threadIdx.x;
    if (i < E0) {
        int p = atomicAdd(&cursor[dst0[i]], 1);
        perm[p] = src0[i];
    } else if (i < E0 + E1) {
        int j = i - E0;
        int p = atomicAdd(&cursor[NN1 + dst1[j]], 1);
        perm[p] = src1[j];
    } else if (i < ETOT) {
        int j = i - E0 - E1;
        int p = atomicAdd(&cursor[NN1 + NN2 + dst2[j]], 1);
        perm[p] = src2[j];
    }
}

// ---------- weight prep: four pre-transposed bf16 halves ----------
// Wt0a[n=256][k=128] from Wl0 (k<100 else 0); Wt0b likewise from Wr0.
// Wt1a[n=256][k=256] from Wl1; Wt1b from Wr1.
__global__ void prep_w(const float* __restrict__ Wl0, const float* __restrict__ Wr0,
                       unsigned short* __restrict__ Wt0a, unsigned short* __restrict__ Wt0b,
                       const float* __restrict__ Wl1, const float* __restrict__ Wr1,
                       unsigned short* __restrict__ Wt1a, unsigned short* __restrict__ Wt1b) {
    int b = blockIdx.x, t = threadIdx.x;
    if (b < 128) {
        int idx = b * 256 + t; int n = idx >> 7, k = idx & 127;
        Wt0a[idx] = f2bf(k < 100 ? Wl0[k * 256 + n] : 0.f);
    } else if (b < 256) {
        int idx = (b - 128) * 256 + t; int n = idx >> 7, k = idx & 127;
        Wt0b[idx] = f2bf(k < 100 ? Wr0[k * 256 + n] : 0.f);
    } else if (b < 512) {
        int idx = (b - 256) * 256 + t; int n = idx >> 8, k = idx & 255;
        Wt1a[idx] = f2bf(Wl1[k * 256 + n]);
    } else {
        int idx = (b - 512) * 256 + t; int n = idx >> 8, k = idx & 255;
        Wt1b[idx] = f2bf(Wr1[k * 256 + n]);
    }
}

// ---------- fused layer 0: gather-mean + dual MFMA GEMM + ReLU -> h1 bf16 ----------
// Block: 128 dst rows x full N=256, 512 threads (8 waves, 2M x 4N of 64x64).
// As[128][136] bf16 (K=128: agg 0..99 | zeros 100..127), re-staged from x for pass 1.
__global__ __launch_bounds__(512) void fused_l0(const float* __restrict__ x,
                                                const int* __restrict__ perm,
                                                const int* __restrict__ ofs,
                                                const unsigned short* __restrict__ Wt0a,
                                                const unsigned short* __restrict__ Wt0b,
                                                const float* __restrict__ bias,
                                                unsigned short* __restrict__ h1) {
    __shared__ unsigned short As[128][136];
    __shared__ unsigned short Bs[256][40];
    int tid = threadIdx.x;
    int lane = tid & 63, wid = tid >> 6;
    int bm = blockIdx.x * 128;

    // ---- gather phase: wave wid aggregates rows [wid*16, wid*16+16) ----
    {
        int g = lane >> 5, l5 = lane & 31;
        bool act = l5 < 25;
        for (int r = 0; r < 16; ++r) {
            int row = wid * 16 + r;
            int node = bm + row;
            int s0 = ofs[node], s1 = ofs[node + 1];
            float inv = 1.0f / fmaxf((float)(s1 - s0), 1.0f);
            f32x4_t A0 = {0.f, 0.f, 0.f, 0.f}, A1 = A0, A2 = A0, A3 = A0;
            int e = s0;
            for (; e + 8 <= s1; e += 8) {
                int p0 = perm[e + 0 + g];
                int p1 = perm[e + 2 + g];
                int p2 = perm[e + 4 + g];
                int p3 = perm[e + 6 + g];
                if (act) {
                    A0 += *reinterpret_cast<const f32x4_t*>(x + (size_t)p0 * 100 + l5 * 4);
                    A1 += *reinterpret_cast<const f32x4_t*>(x + (size_t)p1 * 100 + l5 * 4);
                    A2 += *reinterpret_cast<const f32x4_t*>(x + (size_t)p2 * 100 + l5 * 4);
                    A3 += *reinterpret_cast<const f32x4_t*>(x + (size_t)p3 * 100 + l5 * 4);
                }
            }
            for (; e < s1; e += 2) {
                int idx = e + g;
                if (idx < s1 && act)
                    A0 += *reinterpret_cast<const f32x4_t*>(x + (size_t)perm[idx] * 100 + l5 * 4);
            }
            f32x4_t a = (A0 + A1) + (A2 + A3);
#pragma unroll
            for (int c = 0; c < 4; c++) a[c] += __shfl_xor(a[c], 32);
            if (lane < 25) {
                ushort4 o;
                o.x = f2bf(a[0] * inv); o.y = f2bf(a[1] * inv);
                o.z = f2bf(a[2] * inv); o.w = f2bf(a[3] * inv);
                *reinterpret_cast<ushort4*>(&As[row][lane * 4]) = o;
            } else if (lane < 32) {
                *reinterpret_cast<ushort4*>(&As[row][100 + (lane - 25) * 4]) = make_ushort4(0, 0, 0, 0);
            }
        }
    }

    f32x4_t acc[4][4];
#pragma unroll
    for (int i = 0; i < 4; i++)
#pragma unroll
        for (int j = 0; j < 4; j++)
#pragma unroll
            for (int r = 0; r < 4; r++) acc[i][j][r] = 0.f;

    int r0 = lane & 15, kg = lane >> 4;
    int wm = (wid >> 2) * 64, wn = (wid & 3) * 64;

    for (int pass = 0; pass < 2; ++pass) {
        const unsigned short* W = pass ? Wt0b : Wt0a;
        if (pass) {
            __syncthreads();   // all pass-0 MFMA done reading As
            // re-stage As <- x rows directly (fp32 -> bf16), 4 threads/row
            int rown = tid >> 2, q = tid & 3;
            for (int c4 = q; c4 < 25; c4 += 4) {
                f32x4_t v = *reinterpret_cast<const f32x4_t*>(x + (size_t)(bm + rown) * 100 + c4 * 4);
                ushort4 o;
                o.x = f2bf(v[0]); o.y = f2bf(v[1]); o.z = f2bf(v[2]); o.w = f2bf(v[3]);
                *reinterpret_cast<ushort4*>(&As[rown][c4 * 4]) = o;
            }
            if (q == 3) {
#pragma unroll
                for (int c4 = 25; c4 < 32; ++c4)
                    *reinterpret_cast<ushort4*>(&As[rown][c4 * 4]) = make_ushort4(0, 0, 0, 0);
            }
        }
        for (int ks = 0; ks < 4; ++ks) {
            __syncthreads();
            // stage Bs: 256 n-rows x 32 k = 1024 int4 chunks
            for (int c = tid; c < 1024; c += 512) {
                int n = c >> 2, k8 = (c & 3) << 3;
                *reinterpret_cast<int4*>(&Bs[n][k8]) =
                    *reinterpret_cast<const int4*>(&W[(size_t)n * 128 + ks * 32 + k8]);
            }
            __syncthreads();
            bf16x8_t af[4], bfv[4];
#pragma unroll
            for (int mi = 0; mi < 4; mi++)
                af[mi] = *reinterpret_cast<const bf16x8_t*>(&As[wm + mi * 16 + r0][ks * 32 + kg * 8]);
#pragma unroll
            for (int ni = 0; ni < 4; ni++)
                bfv[ni] = *reinterpret_cast<const bf16x8_t*>(&Bs[wn + ni * 16 + r0][kg * 8]);
#pragma unroll
            for (int mi = 0; mi < 4; mi++)
#pragma unroll
                for (int ni = 0; ni < 4; ni++)
                    acc[mi][ni] = __builtin_amdgcn_mfma_f32_16x16x32_bf16(af[mi], bfv[ni], acc[mi][ni], 0, 0, 0);
        }
    }

    int cc = lane & 15, rr = (lane >> 4) * 4;
#pragma unroll
    for (int mi = 0; mi < 4; mi++) {
#pragma unroll
        for (int ni = 0; ni < 4; ni++) {
            int col = wn + ni * 16 + cc;
            float b = bias[col];
#pragma unroll
            for (int j = 0; j < 4; j++) {
                int row = bm + wm + mi * 16 + rr + j;
                float v = fmaxf(acc[mi][ni][j] + b, 0.f);
                h1[(size_t)row * 256 + col] = f2bf(v);
            }
        }
    }
}

// ---------- fused layer 1: gather-mean(h1) + dual MFMA GEMM + ReLU -> h2 fp32 ----------
// Block: 64 dst rows x 128 cols, grid (2,128), 512 threads (8 waves, 2M x 4N of 32x32).
// As[64][264] bf16 (K=256 agg), re-staged from h1 rows for pass 1.
__global__ __launch_bounds__(512) void fused_l1(const unsigned short* __restrict__ h1,
                                                const int* __restrict__ perm,
                                                const int* __restrict__ ofs,
                                                const unsigned short* __restrict__ Wt1a,
                                                const unsigned short* __restrict__ Wt1b,
                                                const float* __restrict__ bias,
                                                float* __restrict__ h2) {
    __shared__ unsigned short As[64][264];
    __shared__ unsigned short Bs[128][40];
    int tid = threadIdx.x;
    int lane = tid & 63, wid = tid >> 6;
    int bm = blockIdx.y * 64, bn = blockIdx.x * 128;

    // ---- gather phase: wave wid aggregates rows [wid*8, wid*8+8) ----
    for (int r = 0; r < 8; ++r) {
        int row = wid * 8 + r;
        int node = bm + row;
        int s0 = ofs[node], s1 = ofs[node + 1];
        float inv = 1.0f / fmaxf((float)(s1 - s0), 1.0f);
        float ac[4][4] = {};
        int e = s0;
        for (; e + 4 <= s1; e += 4) {
            ushort4 v[4];
#pragma unroll
            for (int u = 0; u < 4; u++)
                v[u] = *reinterpret_cast<const ushort4*>(h1 + (size_t)perm[e + u] * 256 + lane * 4);
#pragma unroll
            for (int u = 0; u < 4; u++) {
                ac[u][0] += bf2f(v[u].x); ac[u][1] += bf2f(v[u].y);
                ac[u][2] += bf2f(v[u].z); ac[u][3] += bf2f(v[u].w);
            }
        }
        for (; e < s1; e++) {
            ushort4 v = *reinterpret_cast<const ushort4*>(h1 + (size_t)perm[e] * 256 + lane * 4);
            ac[0][0] += bf2f(v.x); ac[0][1] += bf2f(v.y);
            ac[0][2] += bf2f(v.z); ac[0][3] += bf2f(v.w);
        }
        ushort4 o;
        o.x = f2bf((ac[0][0] + ac[1][0] + ac[2][0] + ac[3][0]) * inv);
        o.y = f2bf((ac[0][1] + ac[1][1] + ac[2][1] + ac[3][1]) * inv);
        o.z = f2bf((ac[0][2] + ac[1][2] + ac[2][2] + ac[3][2]) * inv);
        o.w = f2bf((ac[0][3] + ac[1][3] + ac[2][3] + ac[3][3]) * inv);
        *reinterpret_cast<ushort4*>(&As[row][lane * 4]) = o;
    }

    f32x4_t acc[2][2];
#pragma unroll
    for (int i = 0; i < 2; i++)
#pragma unroll
        for (int j = 0; j < 2; j++)
#pragma unroll
            for (int r = 0; r < 4; r++) acc[i][j][r] = 0.f;

    int r0 = lane & 15, kg = lane >> 4;
    int wm = (wid >> 2) * 32, wn = (wid & 3) * 32;

    for (int pass = 0; pass < 2; ++pass) {
        const unsigned short* W = pass ? Wt1b : Wt1a;
        if (pass) {
            __syncthreads();   // pass-0 MFMA done reading As
            // re-stage As <- h1 rows directly: 64 rows x 32 int4 chunks = 2048
            for (int c = tid; c < 2048; c += 512) {
                int row = c >> 5, k8 = (c & 31) << 3;
                *reinterpret_cast<int4*>(&As[row][k8]) =
                    *reinterpret_cast<const int4*>(&h1[(size_t)(bm + row) * 256 + k8]);
            }
        }
        for (int ks = 0; ks < 8; ++ks) {
            __syncthreads();
            // stage Bs: 128 n-rows x 32 k = 512 int4 chunks
            {
                int c = tid;
                int n = c >> 2, k8 = (c & 3) << 3;
                *reinterpret_cast<int4*>(&Bs[n][k8]) =
                    *reinterpret_cast<const int4*>(&W[(size_t)(bn + n) * 256 + ks * 32 + k8]);
            }
            __syncthreads();
            bf16x8_t af[2], bfv[2];
#pragma unroll
            for (int mi = 0; mi < 2; mi++)
                af[mi] = *reinterpret_cast<const bf16x8_t*>(&As[wm + mi * 16 + r0][ks * 32 + kg * 8]);
#pragma unroll
            for (int ni = 0; ni < 2; ni++)
                bfv[ni] = *reinterpret_cast<const bf16x8_t*>(&Bs[wn + ni * 16 + r0][kg * 8]);
#pragma unroll
            for (int mi = 0; mi < 2; mi++)
#pragma unroll
                for (int ni = 0; ni < 2; ni++)
                    acc[mi][ni] = __builtin_amdgcn_mfma_f32_16x16x32_bf16(af[mi], bfv[ni], acc[mi][ni], 0, 0, 0);
        }
    }

    int cc = lane & 15, rr = (lane >> 4) * 4;
#pragma unroll
    for (int mi = 0; mi < 2; mi++) {
#pragma unroll
        for (int ni = 0; ni < 2; ni++) {
            int col = bn + wn + ni * 16 + cc;
            float b = bias[col];
#pragma unroll
            for (int j = 0; j < 4; j++) {
                int row = bm + wm + mi * 16 + rr + j;
                h2[(size_t)row * 256 + col] = fmaxf(acc[mi][ni][j] + b, 0.f);
            }
        }
    }
}

// ---------- layer-2 aggregate: h2 fp32 (D=256) ----------
__global__ void agg_vec4_256(const float* __restrict__ x, const int* __restrict__ perm,
                             const int* __restrict__ ofs, float* __restrict__ agg, int nrows) {
    int wave = (blockIdx.x * blockDim.x + threadIdx.x) >> 6;
    int lane = threadIdx.x & 63;
    if (wave >= nrows) return;
    int s0 = ofs[wave], s1 = ofs[wave + 1];
    float4 acc = make_float4(0.f, 0.f, 0.f, 0.f);
    for (int e = s0; e < s1; e++) {
        const float4* xr = (const float4*)(x + (size_t)perm[e] * 256);
        float4 v = xr[lane];
        acc.x += v.x; acc.y += v.y; acc.z += v.z; acc.w += v.w;
    }
    float inv = 1.0f / fmaxf((float)(s1 - s0), 1.0f);
    acc.x *= inv; acc.y *= inv; acc.z *= inv; acc.w *= inv;
    ((float4*)(agg + (size_t)wave * 256))[lane] = acc;
}

// ---------- layer-2: fp32 dual GEMM with fused log_softmax ----------
__global__ __launch_bounds__(256) void gemm2_fused(const float* __restrict__ A1, const float* __restrict__ W1, int K1,
                                                   const float* __restrict__ A2, const float* __restrict__ W2, int K2,
                                                   const float* __restrict__ bias, float* __restrict__ out,
                                                   int M, int N) {
    __shared__ float As[16][65];
    __shared__ float Bs[16][64];
    int tid = threadIdx.x;
    int tx = tid & 15, ty = tid >> 4;
    int bm = blockIdx.y * 64;
    float acc[4][4] = {};
    for (int pass = 0; pass < 2; ++pass) {
        const float* A = pass ? A2 : A1;
        const float* W = pass ? W2 : W1;
        int K = pass ? K2 : K1;
        for (int k0 = 0; k0 < K; k0 += 16) {
#pragma unroll
            for (int i = 0; i < 4; i++) {
                int L = i * 256 + tid;
                int m = L >> 4, k = L & 15;
                int gm = bm + m, gk = k0 + k;
                float v = 0.f;
                if (gm < M && gk < K) v = A[(size_t)gm * K + gk];
                As[k][m] = v;
            }
#pragma unroll
            for (int i = 0; i < 4; i++) {
                int L = i * 256 + tid;
                int n = L & 63, k = L >> 6;
                int gk = k0 + k;
                float v = 0.f;
                if (gk < K && n < N) v = W[(size_t)gk * N + n];
                Bs[k][n] = v;
            }
            __syncthreads();
#pragma unroll
            for (int k = 0; k < 16; k++) {
                float a[4], b[4];
#pragma unroll
                for (int i = 0; i < 4; i++) a[i] = As[k][ty * 4 + i];
#pragma unroll
                for (int j = 0; j < 4; j++) b[j] = Bs[k][tx * 4 + j];
#pragma unroll
                for (int i = 0; i < 4; i++)
#pragma unroll
                    for (int j = 0; j < 4; j++) acc[i][j] += a[i] * b[j];
            }
            __syncthreads();
        }
    }
#pragma unroll
    for (int i = 0; i < 4; i++) {
        int gm = bm + ty * 4 + i;
        float vals[4];
        float vmax = -1e30f;
#pragma unroll
        for (int j = 0; j < 4; j++) {
            int gn = tx * 4 + j;
            vals[j] = (gn < N) ? acc[i][j] + bias[gn] : -1e30f;
            vmax = fmaxf(vmax, vals[j]);
        }
#pragma unroll
        for (int o = 1; o < 16; o <<= 1) vmax = fmaxf(vmax, __shfl_xor(vmax, o));
        float se = 0.f;
#pragma unroll
        for (int j = 0; j < 4; j++) {
            int gn = tx * 4 + j;
            if (gn < N) se += expf(vals[j] - vmax);
        }
#pragma unroll
        for (int o = 1; o < 16; o <<= 1) se += __shfl_xor(se, o);
        float ls = logf(se);
#pragma unroll
        for (int j = 0; j < 4; j++) {
            int gn = tx * 4 + j;
            if (gn < N && gm < M) out[(size_t)gm * N + gn] = vals[j] - vmax - ls;
        }
    }
}

extern "C" void kernel_launch(void* const* d_in, const int* in_sizes, int n_in,
                              void* d_out, int out_size, void* d_ws, size_t ws_size,
                              hipStream_t stream) {
    const float* x   = (const float*)d_in[0];
    const int* src0  = (const int*)d_in[1];
    const int* dst0  = (const int*)d_in[2];
    const int* src1  = (const int*)d_in[3];
    const int* dst1  = (const int*)d_in[4];
    const int* src2  = (const int*)d_in[5];
    const int* dst2  = (const int*)d_in[6];
    const float* Wl0 = (const float*)d_in[7];
    const float* bl0 = (const float*)d_in[8];
    const float* Wr0 = (const float*)d_in[9];
    const float* Wl1 = (const float*)d_in[10];
    const float* bl1 = (const float*)d_in[11];
    const float* Wr1 = (const float*)d_in[12];
    const float* Wl2 = (const float*)d_in[13];
    const float* bl2 = (const float*)d_in[14];
    const float* Wr2 = (const float*)d_in[15];
    float* out = (float*)d_out;

    // ---- workspace layout ----
    char* p = (char*)d_ws;
    auto alloc = [&](size_t bytes) { char* r = p; p += (bytes + 255) & ~(size_t)255; return r; };
    unsigned short* h1   = (unsigned short*)alloc((size_t)NN1 * 256 * 2);  // layer-0 out bf16
    float* h2    = (float*)alloc((size_t)NN2 * 256 * 4);                   // layer-1 out fp32
    float* agg2  = (float*)alloc((size_t)NN3 * 256 * 4);
    unsigned short* Wt0a = (unsigned short*)alloc(256 * 128 * 2);
    unsigned short* Wt0b = (unsigned short*)alloc(256 * 128 * 2);
    unsigned short* Wt1a = (unsigned short*)alloc(256 * 256 * 2);
    unsigned short* Wt1b = (unsigned short*)alloc(256 * 256 * 2);
    int* cnt    = (int*)alloc((size_t)NTOT * 4);
    int* ofs    = (int*)alloc((size_t)(NTOT + 1) * 4);
    int* cursor = (int*)alloc((size_t)(NTOT + 1) * 4);
    int* sums   = (int*)alloc(128 * 4);
    int* perm   = (int*)alloc((size_t)ETOT * 4);

    // ---- weight prep + fused CSR build ----
    prep_w<<<768, 256, 0, stream>>>(Wl0, Wr0, Wt0a, Wt0b, Wl1, Wr1, Wt1a, Wt1b);
    hipMemsetAsync(cnt, 0, (size_t)NTOT * 4, stream);
    count_all<<<cdiv(ETOT, 256), 256, 0, stream>>>(dst0, dst1, dst2, cnt);
    int nb = cdiv(NTOT, 1024);   // 73
    scan1<<<nb, 1024, 0, stream>>>(cnt, NTOT, ofs, sums);
    scan3<<<cdiv(NTOT, 256), 256, 0, stream>>>(sums, NTOT, ofs, cursor);
    scatter_all<<<cdiv(ETOT, 256), 256, 0, stream>>>(src0, dst0, src1, dst1, src2, dst2, cursor, perm);

    // ---- layer 0 (fused gather + dual GEMM + ReLU) ----
    fused_l0<<<NN1 / 128, 512, 0, stream>>>(x, perm, ofs, Wt0a, Wt0b, bl0, h1);

    // ---- layer 1 (fused gather + dual GEMM + ReLU) ----
    {
        dim3 grid(2, NN2 / 64);
        fused_l1<<<grid, 512, 0, stream>>>(h1, perm, ofs + NN1, Wt1a, Wt1b, bl1, h2);
    }

    // ---- layer 2 (fp32, fused log_softmax) ----
    agg_vec4_256<<<cdiv(NN3 * 64, 256), 256, 0, stream>>>(h2, perm, ofs + NN1 + NN2, agg2, NN3);
    {
        dim3 grid(1, cdiv(NN3, 64));
        gemm2_fused<<<grid, 256, 0, stream>>>(agg2, Wl2, 256, h2, Wr2, 256, bl2, out, NN3, 47);
    }
}